// Round 4
// baseline (2829.673 us; speedup 1.0000x reference)
//
#include <hip/hip_runtime.h>
#include <hip/hip_cooperative_groups.h>
#include <math.h>

namespace cg = cooperative_groups;

#define B_ 64
#define T_ 128
#define I_ 1024
#define H_ 4096
#define XCDS 8

#define RNN_BLOCKS 256
#define RNN_THREADS 1024

#define MAXIT_IH 8    // 64 nnz/row registerized (Poisson(32)); tail fallback beyond

// ---------------- helpers ----------------
__device__ __forceinline__ void load4x16_sc0(const float* p0, const float* p1,
                                             const float* p2, const float* p3,
                                             float4& a, float4& b, float4& c, float4& d) {
    asm volatile(
        "global_load_dwordx4 %0, %4, off sc0\n\t"
        "global_load_dwordx4 %1, %5, off sc0\n\t"
        "global_load_dwordx4 %2, %6, off sc0\n\t"
        "global_load_dwordx4 %3, %7, off sc0\n\t"
        "s_waitcnt vmcnt(0)"
        : "=&v"(a), "=&v"(b), "=&v"(c), "=&v"(d)
        : "v"(p0), "v"(p1), "v"(p2), "v"(p3));
}

// ---------------- transpose x (B,T,I) -> xT2 (T, 8, I, 8) ----------------
__global__ void transpose_x(const float* __restrict__ x, float* __restrict__ xT2) {
    __shared__ float lds[8][129];
    int t  = blockIdx.z;
    int bg = blockIdx.y;
    int i0 = blockIdx.x * 128;
    int tx = threadIdx.x;   // 0..127
    int ty = threadIdx.y;   // 0..7
    int b = bg * 8 + ty;
    lds[ty][tx] = x[(size_t)b * T_ * I_ + (size_t)t * I_ + i0 + tx];
    __syncthreads();
    int n  = ty * 128 + tx;
    int ii = n >> 3;
    int bs = n & 7;
    xT2[(((size_t)t * 8 + bg) * I_ + i0 + ii) * 8 + bs] = lds[bs][ii];
}

// ---------------- CSR build ----------------
__global__ void hist_rows(const int* __restrict__ rows, int nnz, int* __restrict__ counts) {
    int k = blockIdx.x * blockDim.x + threadIdx.x;
    if (k < nnz) atomicAdd(&counts[rows[k]], 1);
}

__global__ void scan_rows(const int* __restrict__ counts, int* __restrict__ rp, int n) {
    int lane = threadIdx.x;      // 0..63
    int chunk = n / 64;
    int base = lane * chunk;
    int s = 0;
    for (int j = 0; j < chunk; ++j) s += counts[base + j];
    int pre = s;
    for (int off = 1; off < 64; off <<= 1) {
        int up = __shfl_up(pre, off, 64);
        if (lane >= off) pre += up;
    }
    int run = pre - s;
    for (int j = 0; j < chunk; ++j) { rp[base + j] = run; run += counts[base + j]; }
    if (lane == 63) rp[n] = run;
}

__global__ void scatter_pack(const int* __restrict__ rows, const int* __restrict__ cols,
                             const float* __restrict__ vals, int nnz,
                             const int* __restrict__ rp, int* __restrict__ cursor,
                             int2* __restrict__ pack) {
    int k = blockIdx.x * blockDim.x + threadIdx.x;
    if (k < nnz) {
        int r = rows[k];
        int pos = atomicAdd(&cursor[r], 1);
        pack[rp[r] + pos] = make_int2(cols[k], __float_as_int(vals[k]));
    }
}

// ---------------- kernel R: persistent XCD-local recurrence, ih FUSED ----------------
// hg layout: hg[((grp*2 + parity)*2 + half) * (H_*4)]
// ih SpMM computed in-loop from xT2 (registerized t-invariant CSR), pre kept in VGPRs.
__global__ __launch_bounds__(RNN_THREADS, 1)
void rnn_steps(const int* __restrict__ hhp, const int2* __restrict__ hhpack,
               const int* __restrict__ ihp, const int2* __restrict__ ihpack,
               const float* __restrict__ bias, const float* __restrict__ xT2,
               float* __restrict__ hg,
               int* __restrict__ regcnt, int* __restrict__ barcnt, int* __restrict__ bargen,
               int* __restrict__ owncnt, int* __restrict__ owngrp,
               float* __restrict__ out) {
    cg::grid_group grid = cg::this_grid();
    __shared__ __align__(16) float sh[H_ * 4];   // 64 KB: h_prev, 4 batch cols of this half

    int tid = threadIdx.x;
    if (tid == 0) {
        int x;
        asm volatile("s_getreg_b32 %0, hwreg(HW_REG_XCC_ID)" : "=s"(x));
        x &= 7;
        int slot = __hip_atomic_fetch_add(&regcnt[x], 1, __ATOMIC_RELAXED,
                                          __HIP_MEMORY_SCOPE_AGENT);
        sh[0] = __int_as_float(x);
        sh[1] = __int_as_float(slot);
    }
    __syncthreads();
    int xcd  = __float_as_int(sh[0]);
    int slot = __float_as_int(sh[1]);
    grid.sync();

    if (blockIdx.x == 0 && tid == 0) {
        int list[XCDS]; int nz = 0;
        for (int j = 0; j < XCDS; ++j) {
            owncnt[j] = 0;
            if (__hip_atomic_load(&regcnt[j], __ATOMIC_RELAXED,
                                  __HIP_MEMORY_SCOPE_AGENT) > 0) list[nz++] = j;
        }
        int rr = 0;
        for (int j = 0; j < XCDS; ++j) {
            int present = __hip_atomic_load(&regcnt[j], __ATOMIC_RELAXED,
                                            __HIP_MEMORY_SCOPE_AGENT) > 0;
            int owner = present ? j : list[rr++ % nz];
            owngrp[owner * 8 + owncnt[owner]] = j;
            owncnt[owner] += 1;
        }
    }
    grid.sync();

    int nblk = __hip_atomic_load(&regcnt[xcd], __ATOMIC_RELAXED, __HIP_MEMORY_SCOPE_AGENT);
    int nown = owncnt[xcd];

    int wave = tid >> 6;
    int lane = tid & 63;
    int rs   = lane >> 3;
    int u    = lane & 7;

    // half assignment (robust to nblk==1)
    int hfbeg, hfend, mywave, nwh;
    if (nblk >= 2) {
        int hf = slot & 1;
        hfbeg = hf; hfend = hf + 1;
        int nhb = (hf == 0) ? ((nblk + 1) >> 1) : (nblk >> 1);
        mywave = (slot >> 1) * (RNN_THREADS / 64) + wave;
        nwh = nhb * (RNN_THREADS / 64);
    } else {
        hfbeg = 0; hfend = 2;
        mywave = wave; nwh = RNN_THREADS / 64;
    }

    // ---- ih: registerize t-invariant CSR for the (typical) 2 static row-groups ----
    int g0 = mywave, g1 = mywave + nwh;
    bool valid0 = g0 < (H_ / 8), valid1 = g1 < (H_ / 8);
    int r0 = g0 * 8 + rs, r1 = g1 * 8 + rs;

    int   icol0[MAXIT_IH]; float ival0[MAXIT_IH];
    int   icol1[MAXIT_IH]; float ival1[MAXIT_IH];
    int ihb0 = 0, ilen0 = 0, ilmax0 = 0, ihb1 = 0, ilen1 = 0, ilmax1 = 0;
    float bias0 = 0.f, bias1 = 0.f;
    if (valid0) {
        ihb0 = ihp[r0]; ilen0 = ihp[r0 + 1] - ihb0;
        int lm = ilen0;
        lm = max(lm, __shfl_xor(lm, 8));
        lm = max(lm, __shfl_xor(lm, 16));
        lm = max(lm, __shfl_xor(lm, 32));
        ilmax0 = __builtin_amdgcn_readfirstlane(lm);
        bias0 = bias[r0];
        #pragma unroll
        for (int it = 0; it < MAXIT_IH; ++it) {
            int2 pk = make_int2(0, 0);
            if (it * 8 + u < ilen0) pk = ihpack[ihb0 + it * 8 + u];
            icol0[it] = pk.x << 5;                 // col * 8 floats * 4 B
            ival0[it] = __int_as_float(pk.y);
        }
    } else {
        #pragma unroll
        for (int it = 0; it < MAXIT_IH; ++it) { icol0[it] = 0; ival0[it] = 0.f; }
    }
    if (valid1) {
        ihb1 = ihp[r1]; ilen1 = ihp[r1 + 1] - ihb1;
        int lm = ilen1;
        lm = max(lm, __shfl_xor(lm, 8));
        lm = max(lm, __shfl_xor(lm, 16));
        lm = max(lm, __shfl_xor(lm, 32));
        ilmax1 = __builtin_amdgcn_readfirstlane(lm);
        bias1 = bias[r1];
        #pragma unroll
        for (int it = 0; it < MAXIT_IH; ++it) {
            int2 pk = make_int2(0, 0);
            if (it * 8 + u < ilen1) pk = ihpack[ihb1 + it * 8 + u];
            icol1[it] = pk.x << 5;
            ival1[it] = __int_as_float(pk.y);
        }
    } else {
        #pragma unroll
        for (int it = 0; it < MAXIT_IH; ++it) { icol1[it] = 0; ival1[it] = 0.f; }
    }
    bool dyn = (mywave + 2 * nwh) < (H_ / 8);   // rare (uneven dispatch only)

    int* bc = &barcnt[xcd * 32];
    int* bgen = &bargen[xcd * 32];

    for (int t = 0; t < T_; ++t) {
        for (int oi = 0; oi < nown; ++oi) {
            int grp = owngrp[xcd * 8 + oi];
            for (int hf = hfbeg; hf < hfend; ++hf) {
                const float* src = hg + (size_t)((grp * 2 + (t & 1)) * 2 + hf) * (H_ * 4);
                float*       dst = hg + (size_t)((grp * 2 + ((t + 1) & 1)) * 2 + hf) * (H_ * 4);
                // base of x_t slice for this (grp, half): 4 batch cols per col index
                const float* xb = xT2 + (((size_t)t * 8 + grp) * I_) * 8 + hf * 4;

                // ---- ih gather-compute (independent of recurrence; overlaps refill) ----
                float p0 = 0.f, p1 = 0.f;
                if (valid0) {
                    float c0 = 0.f, c1 = 0.f, c2 = 0.f, c3 = 0.f;
                    #pragma unroll
                    for (int it = 0; it < MAXIT_IH; ++it) {
                        float4 xv = *(const float4*)((const char*)xb + icol0[it]);
                        float v = ival0[it];
                        c0 += v * xv.x; c1 += v * xv.y; c2 += v * xv.z; c3 += v * xv.w;
                    }
                    if (ilmax0 > 8 * MAXIT_IH) {   // rare tail, same summation order
                        int kk = ihb0 + 8 * MAXIT_IH + u;
                        for (int i = 8 * MAXIT_IH; i < ilmax0; i += 8, kk += 8) {
                            int2 pk = make_int2(0, 0);
                            if (i + u < ilen0) pk = ihpack[kk];
                            float4 xv = *(const float4*)((const char*)xb + ((size_t)pk.x << 5));
                            float v = __int_as_float(pk.y);
                            c0 += v * xv.x; c1 += v * xv.y; c2 += v * xv.z; c3 += v * xv.w;
                        }
                    }
                    #pragma unroll
                    for (int off = 1; off <= 4; off <<= 1) {
                        c0 += __shfl_xor(c0, off);
                        c1 += __shfl_xor(c1, off);
                        c2 += __shfl_xor(c2, off);
                        c3 += __shfl_xor(c3, off);
                    }
                    if (u < 4)
                        p0 = ((u == 0) ? c0 : (u == 1) ? c1 : (u == 2) ? c2 : c3) + bias0;
                }
                if (valid1) {
                    float c0 = 0.f, c1 = 0.f, c2 = 0.f, c3 = 0.f;
                    #pragma unroll
                    for (int it = 0; it < MAXIT_IH; ++it) {
                        float4 xv = *(const float4*)((const char*)xb + icol1[it]);
                        float v = ival1[it];
                        c0 += v * xv.x; c1 += v * xv.y; c2 += v * xv.z; c3 += v * xv.w;
                    }
                    if (ilmax1 > 8 * MAXIT_IH) {
                        int kk = ihb1 + 8 * MAXIT_IH + u;
                        for (int i = 8 * MAXIT_IH; i < ilmax1; i += 8, kk += 8) {
                            int2 pk = make_int2(0, 0);
                            if (i + u < ilen1) pk = ihpack[kk];
                            float4 xv = *(const float4*)((const char*)xb + ((size_t)pk.x << 5));
                            float v = __int_as_float(pk.y);
                            c0 += v * xv.x; c1 += v * xv.y; c2 += v * xv.z; c3 += v * xv.w;
                        }
                    }
                    #pragma unroll
                    for (int off = 1; off <= 4; off <<= 1) {
                        c0 += __shfl_xor(c0, off);
                        c1 += __shfl_xor(c1, off);
                        c2 += __shfl_xor(c2, off);
                        c3 += __shfl_xor(c3, off);
                    }
                    if (u < 4)
                        p1 = ((u == 0) ? c0 : (u == 1) ? c1 : (u == 2) ? c2 : c3) + bias1;
                }

                // ---- fill sh with h_prev (sc0: bypass stale L1, hit local L2) ----
                __syncthreads();   // prior readers of sh are done
                {
                    float4 v0, v1, v2, v3;
                    const float* q0 = src + (size_t)(0 * 1024 + tid) * 4;
                    const float* q1 = src + (size_t)(1 * 1024 + tid) * 4;
                    const float* q2 = src + (size_t)(2 * 1024 + tid) * 4;
                    const float* q3 = src + (size_t)(3 * 1024 + tid) * 4;
                    load4x16_sc0(q0, q1, q2, q3, v0, v1, v2, v3);
                    float4* s4 = (float4*)sh;
                    s4[0 * 1024 + tid] = v0;
                    s4[1 * 1024 + tid] = v1;
                    s4[2 * 1024 + tid] = v2;
                    s4[3 * 1024 + tid] = v3;
                }
                __syncthreads();   // sh ready

                // ---- hh SpMM (round-0 body; hhpack stream preserved) + combine ----
                if (valid0) {
                    int hb = hhp[r0], he = hhp[r0 + 1];
                    int len = he - hb;
                    int lmax = len;
                    lmax = max(lmax, __shfl_xor(lmax, 8));
                    lmax = max(lmax, __shfl_xor(lmax, 16));
                    lmax = max(lmax, __shfl_xor(lmax, 32));
                    float a0 = 0.f, a1 = 0.f, a2 = 0.f, a3 = 0.f;
                    int kk = hb + u;
                    for (int i = 0; i < lmax; i += 8, kk += 8) {
                        int2 pk = make_int2(0, 0);
                        if (i + u < len) pk = hhpack[kk];
                        float4 hv = ((const float4*)sh)[pk.x];
                        float v = __int_as_float(pk.y);
                        a0 += v * hv.x; a1 += v * hv.y; a2 += v * hv.z; a3 += v * hv.w;
                    }
                    #pragma unroll
                    for (int off = 1; off <= 4; off <<= 1) {
                        a0 += __shfl_xor(a0, off);
                        a1 += __shfl_xor(a1, off);
                        a2 += __shfl_xor(a2, off);
                        a3 += __shfl_xor(a3, off);
                    }
                    if (u < 4) {
                        float acc = (u == 0) ? a0 : (u == 1) ? a1 : (u == 2) ? a2 : a3;
                        float h = tanhf(acc + p0);
                        dst[(size_t)r0 * 4 + u] = h;
                        int b = grp * 8 + hf * 4 + u;
                        out[(size_t)b * T_ * H_ + (size_t)t * H_ + r0] = h;
                    }
                }
                if (valid1) {
                    int hb = hhp[r1], he = hhp[r1 + 1];
                    int len = he - hb;
                    int lmax = len;
                    lmax = max(lmax, __shfl_xor(lmax, 8));
                    lmax = max(lmax, __shfl_xor(lmax, 16));
                    lmax = max(lmax, __shfl_xor(lmax, 32));
                    float a0 = 0.f, a1 = 0.f, a2 = 0.f, a3 = 0.f;
                    int kk = hb + u;
                    for (int i = 0; i < lmax; i += 8, kk += 8) {
                        int2 pk = make_int2(0, 0);
                        if (i + u < len) pk = hhpack[kk];
                        float4 hv = ((const float4*)sh)[pk.x];
                        float v = __int_as_float(pk.y);
                        a0 += v * hv.x; a1 += v * hv.y; a2 += v * hv.z; a3 += v * hv.w;
                    }
                    #pragma unroll
                    for (int off = 1; off <= 4; off <<= 1) {
                        a0 += __shfl_xor(a0, off);
                        a1 += __shfl_xor(a1, off);
                        a2 += __shfl_xor(a2, off);
                        a3 += __shfl_xor(a3, off);
                    }
                    if (u < 4) {
                        float acc = (u == 0) ? a0 : (u == 1) ? a1 : (u == 2) ? a2 : a3;
                        float h = tanhf(acc + p1);
                        dst[(size_t)r1 * 4 + u] = h;
                        int b = grp * 8 + hf * 4 + u;
                        out[(size_t)b * T_ * H_ + (size_t)t * H_ + r1] = h;
                    }
                }
                if (dyn) {   // rare: >2 row-groups/wave — fully dynamic hh + ih
                    for (int g = mywave + 2 * nwh; g < H_ / 8; g += nwh) {
                        int r  = g * 8 + rs;
                        int hb = hhp[r], he = hhp[r + 1];
                        int len = he - hb;
                        int lmax = len;
                        lmax = max(lmax, __shfl_xor(lmax, 8));
                        lmax = max(lmax, __shfl_xor(lmax, 16));
                        lmax = max(lmax, __shfl_xor(lmax, 32));
                        float a0 = 0.f, a1 = 0.f, a2 = 0.f, a3 = 0.f;
                        int kk = hb + u;
                        for (int i = 0; i < lmax; i += 8, kk += 8) {
                            int2 pk = make_int2(0, 0);
                            if (i + u < len) pk = hhpack[kk];
                            float4 hv = ((const float4*)sh)[pk.x];
                            float v = __int_as_float(pk.y);
                            a0 += v * hv.x; a1 += v * hv.y; a2 += v * hv.z; a3 += v * hv.w;
                        }
                        // ih inline (dynamic)
                        int ib = ihp[r], ie = ihp[r + 1];
                        int il = ie - ib;
                        int ilm = il;
                        ilm = max(ilm, __shfl_xor(ilm, 8));
                        ilm = max(ilm, __shfl_xor(ilm, 16));
                        ilm = max(ilm, __shfl_xor(ilm, 32));
                        float c0 = 0.f, c1 = 0.f, c2 = 0.f, c3 = 0.f;
                        int kk2 = ib + u;
                        for (int i = 0; i < ilm; i += 8, kk2 += 8) {
                            int2 pk = make_int2(0, 0);
                            if (i + u < il) pk = ihpack[kk2];
                            float4 xv = *(const float4*)((const char*)xb + ((size_t)pk.x << 5));
                            float v = __int_as_float(pk.y);
                            c0 += v * xv.x; c1 += v * xv.y; c2 += v * xv.z; c3 += v * xv.w;
                        }
                        #pragma unroll
                        for (int off = 1; off <= 4; off <<= 1) {
                            a0 += __shfl_xor(a0, off);
                            a1 += __shfl_xor(a1, off);
                            a2 += __shfl_xor(a2, off);
                            a3 += __shfl_xor(a3, off);
                            c0 += __shfl_xor(c0, off);
                            c1 += __shfl_xor(c1, off);
                            c2 += __shfl_xor(c2, off);
                            c3 += __shfl_xor(c3, off);
                        }
                        if (u < 4) {
                            float acc = (u == 0) ? a0 : (u == 1) ? a1 : (u == 2) ? a2 : a3;
                            float pv  = ((u == 0) ? c0 : (u == 1) ? c1 : (u == 2) ? c2 : c3)
                                        + bias[r];
                            float h = tanhf(acc + pv);
                            dst[(size_t)r * 4 + u] = h;
                            int b = grp * 8 + hf * 4 + u;
                            out[(size_t)b * T_ * H_ + (size_t)t * H_ + r] = h;
                        }
                    }
                }
            }
        }

        // ---- per-XCD barrier (round-0 proven protocol: full drain) ----
        __syncthreads();   // drains this block's h stores to L2 (vmcnt(0) before s_barrier)
        if (tid == 0) {
            asm volatile("s_waitcnt vmcnt(0)" ::: "memory");
            int target = t + 1;
            int old = __hip_atomic_fetch_add(bc, 1, __ATOMIC_RELAXED,
                                             __HIP_MEMORY_SCOPE_AGENT);
            if (old == nblk - 1) {
                __hip_atomic_store(bc, 0, __ATOMIC_RELAXED, __HIP_MEMORY_SCOPE_AGENT);
                __hip_atomic_store(bgen, target, __ATOMIC_RELAXED, __HIP_MEMORY_SCOPE_AGENT);
            } else {
                while (__hip_atomic_load(bgen, __ATOMIC_RELAXED,
                                         __HIP_MEMORY_SCOPE_AGENT) < target) {
                    __builtin_amdgcn_s_sleep(1);
                }
            }
        }
        __syncthreads();
    }
}

// ---------------- host launch ----------------
extern "C" void kernel_launch(void* const* d_in, const int* in_sizes, int n_in,
                              void* d_out, int out_size, void* d_ws, size_t ws_size,
                              hipStream_t stream) {
    const float* x       = (const float*)d_in[0];
    const float* ih_vals = (const float*)d_in[1];
    const float* hh_vals = (const float*)d_in[2];
    const float* hh_bias = (const float*)d_in[3];
    const int*   ih_rows = (const int*)d_in[4];
    const int*   ih_cols = (const int*)d_in[5];
    const int*   hh_rows = (const int*)d_in[6];
    const int*   hh_cols = (const int*)d_in[7];
    float* out = (float*)d_out;

    const int nnz_ih = in_sizes[1];
    const int nnz_hh = in_sizes[2];

    char* ws = (char*)d_ws;
    size_t off = 0;
    auto alloc = [&](size_t bytes) -> void* {
        off = (off + 255) & ~(size_t)255;
        void* p = ws + off;
        off += bytes;
        return p;
    };

    float* xT2   = (float*)alloc((size_t)T_ * 8 * I_ * 8 * sizeof(float));
    int*   ih_rp = (int*)  alloc((H_ + 1) * sizeof(int));
    int*   hh_rp = (int*)  alloc((H_ + 1) * sizeof(int));

    const int ZINTS = 4 * H_ + 64 + 8 * 32 + 8 * 32 + 8 + 64;
    int* zbase  = (int*)alloc((size_t)ZINTS * sizeof(int));
    int* ih_cnt = zbase;
    int* ih_cur = zbase + H_;
    int* hh_cnt = zbase + 2 * H_;
    int* hh_cur = zbase + 3 * H_;
    int* regcnt = zbase + 4 * H_;
    int* barcnt = regcnt + 64;
    int* bargen = barcnt + 8 * 32;
    int* owncnt = bargen + 8 * 32;
    int* owngrp = owncnt + 8;

    int2* ih_pack = (int2*)alloc((size_t)nnz_ih * sizeof(int2));
    int2* hh_pack = (int2*)alloc((size_t)nnz_hh * sizeof(int2));
    float* hg     = (float*)alloc((size_t)XCDS * 2 * 2 * H_ * 4 * sizeof(float));  // 2 MB

    hipMemsetAsync(zbase, 0, (size_t)ZINTS * sizeof(int), stream);
    hipMemsetAsync(hg, 0, (size_t)XCDS * 2 * 2 * H_ * 4 * sizeof(float), stream);

    transpose_x<<<dim3(I_ / 128, 8, T_), dim3(128, 8), 0, stream>>>(x, xT2);

    hist_rows<<<(nnz_ih + 255) / 256, 256, 0, stream>>>(ih_rows, nnz_ih, ih_cnt);
    scan_rows<<<1, 64, 0, stream>>>(ih_cnt, ih_rp, H_);
    scatter_pack<<<(nnz_ih + 255) / 256, 256, 0, stream>>>(ih_rows, ih_cols, ih_vals, nnz_ih,
                                                           ih_rp, ih_cur, ih_pack);
    hist_rows<<<(nnz_hh + 255) / 256, 256, 0, stream>>>(hh_rows, nnz_hh, hh_cnt);
    scan_rows<<<1, 64, 0, stream>>>(hh_cnt, hh_rp, H_);
    scatter_pack<<<(nnz_hh + 255) / 256, 256, 0, stream>>>(hh_rows, hh_cols, hh_vals, nnz_hh,
                                                           hh_rp, hh_cur, hh_pack);

    void* kargs[] = {
        (void*)&hh_rp, (void*)&hh_pack,
        (void*)&ih_rp, (void*)&ih_pack,
        (void*)&hh_bias, (void*)&xT2,
        (void*)&hg,
        (void*)&regcnt, (void*)&barcnt, (void*)&bargen,
        (void*)&owncnt, (void*)&owngrp,
        (void*)&out,
    };
    hipLaunchCooperativeKernel((const void*)rnn_steps, dim3(RNN_BLOCKS), dim3(RNN_THREADS),
                               kargs, 0, stream);
}

// Round 5
// 1930.791 us; speedup vs baseline: 1.4656x; 1.4656x over previous
//
#include <hip/hip_runtime.h>
#include <hip/hip_cooperative_groups.h>
#include <math.h>

namespace cg = cooperative_groups;

#define B_ 64
#define T_ 128
#define I_ 1024
#define H_ 4096
#define XCDS 8

#define RNN_BLOCKS 256
#define RNN_THREADS 1024

#define MAXIT_IH 8    // 64 nnz/row registerized (Poisson(32)); tail fallback beyond

// ---------------- helpers ----------------
__device__ __forceinline__ unsigned short f2bf(float f) {
    unsigned int u = __float_as_uint(f);
    unsigned int r = (u + 0x7fffu + ((u >> 16) & 1u)) >> 16;
    return (unsigned short)r;
}

__device__ __forceinline__ void load4x16_sc0(const float* p0, const float* p1,
                                             const float* p2, const float* p3,
                                             float4& a, float4& b, float4& c, float4& d) {
    asm volatile(
        "global_load_dwordx4 %0, %4, off sc0\n\t"
        "global_load_dwordx4 %1, %5, off sc0\n\t"
        "global_load_dwordx4 %2, %6, off sc0\n\t"
        "global_load_dwordx4 %3, %7, off sc0\n\t"
        "s_waitcnt vmcnt(0)"
        : "=&v"(a), "=&v"(b), "=&v"(c), "=&v"(d)
        : "v"(p0), "v"(p1), "v"(p2), "v"(p3));
}

// ---------------- transpose x (B,T,I) -> xT2 (T, 8, I, 8) ----------------
__global__ void transpose_x(const float* __restrict__ x, float* __restrict__ xT2) {
    __shared__ float lds[8][129];
    int t  = blockIdx.z;
    int bg = blockIdx.y;
    int i0 = blockIdx.x * 128;
    int tx = threadIdx.x;   // 0..127
    int ty = threadIdx.y;   // 0..7
    int b = bg * 8 + ty;
    lds[ty][tx] = x[(size_t)b * T_ * I_ + (size_t)t * I_ + i0 + tx];
    __syncthreads();
    int n  = ty * 128 + tx;
    int ii = n >> 3;
    int bs = n & 7;
    xT2[(((size_t)t * 8 + bg) * I_ + i0 + ii) * 8 + bs] = lds[bs][ii];
}

// ---------------- CSR build ----------------
__global__ void hist_rows(const int* __restrict__ rows, int nnz, int* __restrict__ counts) {
    int k = blockIdx.x * blockDim.x + threadIdx.x;
    if (k < nnz) atomicAdd(&counts[rows[k]], 1);
}

__global__ void scan_rows(const int* __restrict__ counts, int* __restrict__ rp, int n) {
    int lane = threadIdx.x;      // 0..63
    int chunk = n / 64;
    int base = lane * chunk;
    int s = 0;
    for (int j = 0; j < chunk; ++j) s += counts[base + j];
    int pre = s;
    for (int off = 1; off < 64; off <<= 1) {
        int up = __shfl_up(pre, off, 64);
        if (lane >= off) pre += up;
    }
    int run = pre - s;
    for (int j = 0; j < chunk; ++j) { rp[base + j] = run; run += counts[base + j]; }
    if (lane == 63) rp[n] = run;
}

__global__ void scatter_pack(const int* __restrict__ rows, const int* __restrict__ cols,
                             const float* __restrict__ vals, int nnz,
                             const int* __restrict__ rp, int* __restrict__ cursor,
                             int2* __restrict__ pack) {
    int k = blockIdx.x * blockDim.x + threadIdx.x;
    if (k < nnz) {
        int r = rows[k];
        int pos = atomicAdd(&cursor[r], 1);
        pack[rp[r] + pos] = make_int2(cols[k], __float_as_int(vals[k]));
    }
}

// ---------------- kernel P: pre[t] = W_ih * x_t + bias  (bf16 out) ----------------
// t-loop inside, CSR slice registerized (t-invariant). NO LDS staging: gather
// float4 pairs straight from xT2 (L1/L2/L3-resident; 32 B per nnz covers both
// halves). No barriers, no bank conflicts.
__global__ __launch_bounds__(256)
void precompute_ih(const float* __restrict__ xT2,
                   const int* __restrict__ rp, const int2* __restrict__ pack,
                   const float* __restrict__ bias,
                   unsigned short* __restrict__ pre) {
    int grp  = blockIdx.y;
    int wave = threadIdx.x >> 6;                  // 0..3
    int lane = threadIdx.x & 63;
    int rs = lane >> 3;   // row within group
    int u  = lane & 7;    // position within window

    int g = blockIdx.x * 4 + wave;                // 0..511
    int r = g * 8 + rs;
    int hb = rp[r];
    int len = rp[r + 1] - hb;
    int lm = len;
    lm = max(lm, __shfl_xor(lm, 8));
    lm = max(lm, __shfl_xor(lm, 16));
    lm = max(lm, __shfl_xor(lm, 32));
    int lmax = __builtin_amdgcn_readfirstlane(lm);
    float bsv = bias[r];

    // registerize the CSR slice (t-invariant): byte offsets pre-shifted
    int   pcol[MAXIT_IH];
    float pval[MAXIT_IH];
    #pragma unroll
    for (int it = 0; it < MAXIT_IH; ++it) {
        int2 pk = make_int2(0, 0);
        if (it * 8 + u < len) pk = pack[hb + it * 8 + u];
        pcol[it] = pk.x << 5;                 // col * 8 floats * 4 B
        pval[it] = __int_as_float(pk.y);
    }

    for (int t = 0; t < T_; ++t) {
        const char* xb = (const char*)(xT2 + ((size_t)t * 8 + grp) * (I_ * 8));

        float a[8];
        #pragma unroll
        for (int j = 0; j < 8; ++j) a[j] = 0.0f;

        // branchless registerized windows (padded lanes read col 0, add +0.0)
        #pragma unroll
        for (int it = 0; it < MAXIT_IH; ++it) {
            const float* gp = (const float*)(xb + pcol[it]);
            float4 x0 = *(const float4*)gp;
            float4 x1 = *(const float4*)(gp + 4);
            float v = pval[it];
            a[0] += v * x0.x; a[1] += v * x0.y; a[2] += v * x0.z; a[3] += v * x0.w;
            a[4] += v * x1.x; a[5] += v * x1.y; a[6] += v * x1.z; a[7] += v * x1.w;
        }
        if (lmax > 8 * MAXIT_IH) {   // rare tail, same summation order
            int kk = hb + 8 * MAXIT_IH + u;
            for (int i = 8 * MAXIT_IH; i < lmax; i += 8, kk += 8) {
                int2 pk = make_int2(0, 0);
                if (i + u < len) pk = pack[kk];
                const float* gp = (const float*)(xb + ((size_t)pk.x << 5));
                float4 x0 = *(const float4*)gp;
                float4 x1 = *(const float4*)(gp + 4);
                float v = __int_as_float(pk.y);
                a[0] += v * x0.x; a[1] += v * x0.y; a[2] += v * x0.z; a[3] += v * x0.w;
                a[4] += v * x1.x; a[5] += v * x1.y; a[6] += v * x1.z; a[7] += v * x1.w;
            }
        }
        #pragma unroll
        for (int off = 1; off <= 4; off <<= 1) {
            #pragma unroll
            for (int j = 0; j < 8; ++j) a[j] += __shfl_xor(a[j], off);
        }
        float sel = (u == 0) ? a[0] : (u == 1) ? a[1] : (u == 2) ? a[2] : (u == 3) ? a[3]
                  : (u == 4) ? a[4] : (u == 5) ? a[5] : (u == 6) ? a[6] : a[7];
        float p = sel + bsv;
        int hf = u >> 2, cc = u & 3;
        pre[((size_t)(grp * 2 + hf) * T_ + t) * (H_ * 4) + (size_t)r * 4 + cc] = f2bf(p);
    }
}

// ---------------- kernel R: persistent XCD-local recurrence ----------------
// EXACT round-0 version (proven 1114-1130 us, FETCH 43 MB — L2-resident hg).
// hg layout: hg[((grp*2 + parity)*2 + half) * (H_*4)]
__global__ __launch_bounds__(RNN_THREADS, 1)
void rnn_steps(const int* __restrict__ hhp, const int2* __restrict__ hhpack,
               const unsigned short* __restrict__ pre,
               float* __restrict__ hg,
               int* __restrict__ regcnt, int* __restrict__ barcnt, int* __restrict__ bargen,
               int* __restrict__ owncnt, int* __restrict__ owngrp,
               float* __restrict__ out) {
    cg::grid_group grid = cg::this_grid();
    __shared__ __align__(16) float sh[H_ * 4];   // 64 KB: h_prev, 4 batch cols of this half

    int tid = threadIdx.x;
    if (tid == 0) {
        int x;
        asm volatile("s_getreg_b32 %0, hwreg(HW_REG_XCC_ID)" : "=s"(x));
        x &= 7;
        int slot = __hip_atomic_fetch_add(&regcnt[x], 1, __ATOMIC_RELAXED,
                                          __HIP_MEMORY_SCOPE_AGENT);
        sh[0] = __int_as_float(x);
        sh[1] = __int_as_float(slot);
    }
    __syncthreads();
    int xcd  = __float_as_int(sh[0]);
    int slot = __float_as_int(sh[1]);
    grid.sync();

    if (blockIdx.x == 0 && tid == 0) {
        int list[XCDS]; int nz = 0;
        for (int j = 0; j < XCDS; ++j) {
            owncnt[j] = 0;
            if (__hip_atomic_load(&regcnt[j], __ATOMIC_RELAXED,
                                  __HIP_MEMORY_SCOPE_AGENT) > 0) list[nz++] = j;
        }
        int rr = 0;
        for (int j = 0; j < XCDS; ++j) {
            int present = __hip_atomic_load(&regcnt[j], __ATOMIC_RELAXED,
                                            __HIP_MEMORY_SCOPE_AGENT) > 0;
            int owner = present ? j : list[rr++ % nz];
            owngrp[owner * 8 + owncnt[owner]] = j;
            owncnt[owner] += 1;
        }
    }
    grid.sync();

    int nblk = __hip_atomic_load(&regcnt[xcd], __ATOMIC_RELAXED, __HIP_MEMORY_SCOPE_AGENT);
    int nown = owncnt[xcd];

    int wave = tid >> 6;
    int lane = tid & 63;
    int rs   = lane >> 3;
    int u    = lane & 7;

    // half assignment (robust to nblk==1)
    int hfbeg, hfend, mywave, nwh;
    if (nblk >= 2) {
        int hf = slot & 1;
        hfbeg = hf; hfend = hf + 1;
        int nhb = (hf == 0) ? ((nblk + 1) >> 1) : (nblk >> 1);
        mywave = (slot >> 1) * (RNN_THREADS / 64) + wave;
        nwh = nhb * (RNN_THREADS / 64);
    } else {
        hfbeg = 0; hfend = 2;
        mywave = wave; nwh = RNN_THREADS / 64;
    }

    int* bc = &barcnt[xcd * 32];
    int* bgen = &bargen[xcd * 32];

    for (int t = 0; t < T_; ++t) {
        for (int oi = 0; oi < nown; ++oi) {
            int grp = owngrp[xcd * 8 + oi];
            for (int hf = hfbeg; hf < hfend; ++hf) {
                const float* src = hg + (size_t)((grp * 2 + (t & 1)) * 2 + hf) * (H_ * 4);
                float*       dst = hg + (size_t)((grp * 2 + ((t + 1) & 1)) * 2 + hf) * (H_ * 4);

                // ---- fill sh with h_prev (sc0: bypass stale L1, hit local L2) ----
                __syncthreads();   // prior readers of sh are done
                {
                    float4 v0, v1, v2, v3;
                    const float* p0 = src + (size_t)(0 * 1024 + tid) * 4;
                    const float* p1 = src + (size_t)(1 * 1024 + tid) * 4;
                    const float* p2 = src + (size_t)(2 * 1024 + tid) * 4;
                    const float* p3 = src + (size_t)(3 * 1024 + tid) * 4;
                    load4x16_sc0(p0, p1, p2, p3, v0, v1, v2, v3);
                    float4* s4 = (float4*)sh;
                    s4[0 * 1024 + tid] = v0;
                    s4[1 * 1024 + tid] = v1;
                    s4[2 * 1024 + tid] = v2;
                    s4[3 * 1024 + tid] = v3;
                }
                __syncthreads();   // sh ready

                // ---- compute: hh SpMM rows + pre + tanh ----
                for (int g = mywave; g < H_ / 8; g += nwh) {
                    int r  = g * 8 + rs;
                    int hb = hhp[r], he = hhp[r + 1];
                    int len = he - hb;
                    int lmax = len;
                    lmax = max(lmax, __shfl_xor(lmax, 8));
                    lmax = max(lmax, __shfl_xor(lmax, 16));
                    lmax = max(lmax, __shfl_xor(lmax, 32));

                    float a0 = 0.f, a1 = 0.f, a2 = 0.f, a3 = 0.f;
                    int kk = hb + u;
                    for (int i = 0; i < lmax; i += 8, kk += 8) {
                        int2 pk = make_int2(0, 0);
                        if (i + u < len) pk = hhpack[kk];
                        float4 hv = ((const float4*)sh)[pk.x];
                        float v = __int_as_float(pk.y);
                        a0 += v * hv.x; a1 += v * hv.y; a2 += v * hv.z; a3 += v * hv.w;
                    }
                    #pragma unroll
                    for (int off = 1; off <= 4; off <<= 1) {
                        a0 += __shfl_xor(a0, off);
                        a1 += __shfl_xor(a1, off);
                        a2 += __shfl_xor(a2, off);
                        a3 += __shfl_xor(a3, off);
                    }
                    if (u < 4) {
                        float acc = (u == 0) ? a0 : (u == 1) ? a1 : (u == 2) ? a2 : a3;
                        float pv = __uint_as_float(
                            (unsigned int)pre[((size_t)(grp * 2 + hf) * T_ + t) * (H_ * 4) +
                                              (size_t)r * 4 + u] << 16);
                        float h = tanhf(acc + pv);
                        dst[(size_t)r * 4 + u] = h;
                        int b = grp * 8 + hf * 4 + u;
                        out[(size_t)b * T_ * H_ + (size_t)t * H_ + r] = h;
                    }
                }
            }
        }

        // ---- per-XCD barrier (no cache maintenance) ----
        __syncthreads();   // drains this block's h stores to L2 (vmcnt(0) before s_barrier)
        if (tid == 0) {
            asm volatile("s_waitcnt vmcnt(0)" ::: "memory");
            int target = t + 1;
            int old = __hip_atomic_fetch_add(bc, 1, __ATOMIC_RELAXED,
                                             __HIP_MEMORY_SCOPE_AGENT);
            if (old == nblk - 1) {
                __hip_atomic_store(bc, 0, __ATOMIC_RELAXED, __HIP_MEMORY_SCOPE_AGENT);
                __hip_atomic_store(bgen, target, __ATOMIC_RELAXED, __HIP_MEMORY_SCOPE_AGENT);
            } else {
                while (__hip_atomic_load(bgen, __ATOMIC_RELAXED,
                                         __HIP_MEMORY_SCOPE_AGENT) < target) {
                    __builtin_amdgcn_s_sleep(1);
                }
            }
        }
        __syncthreads();
    }
}

// ---------------- host launch ----------------
extern "C" void kernel_launch(void* const* d_in, const int* in_sizes, int n_in,
                              void* d_out, int out_size, void* d_ws, size_t ws_size,
                              hipStream_t stream) {
    const float* x       = (const float*)d_in[0];
    const float* ih_vals = (const float*)d_in[1];
    const float* hh_vals = (const float*)d_in[2];
    const float* hh_bias = (const float*)d_in[3];
    const int*   ih_rows = (const int*)d_in[4];
    const int*   ih_cols = (const int*)d_in[5];
    const int*   hh_rows = (const int*)d_in[6];
    const int*   hh_cols = (const int*)d_in[7];
    float* out = (float*)d_out;

    const int nnz_ih = in_sizes[1];
    const int nnz_hh = in_sizes[2];

    char* ws = (char*)d_ws;
    size_t off = 0;
    auto alloc = [&](size_t bytes) -> void* {
        off = (off + 255) & ~(size_t)255;
        void* p = ws + off;
        off += bytes;
        return p;
    };

    float* xT2   = (float*)alloc((size_t)T_ * 8 * I_ * 8 * sizeof(float));
    int*   ih_rp = (int*)  alloc((H_ + 1) * sizeof(int));
    int*   hh_rp = (int*)  alloc((H_ + 1) * sizeof(int));

    const int ZINTS = 4 * H_ + 64 + 8 * 32 + 8 * 32 + 8 + 64;
    int* zbase  = (int*)alloc((size_t)ZINTS * sizeof(int));
    int* ih_cnt = zbase;
    int* ih_cur = zbase + H_;
    int* hh_cnt = zbase + 2 * H_;
    int* hh_cur = zbase + 3 * H_;
    int* regcnt = zbase + 4 * H_;
    int* barcnt = regcnt + 64;
    int* bargen = barcnt + 8 * 32;
    int* owncnt = bargen + 8 * 32;
    int* owngrp = owncnt + 8;

    int2* ih_pack = (int2*)alloc((size_t)nnz_ih * sizeof(int2));
    int2* hh_pack = (int2*)alloc((size_t)nnz_hh * sizeof(int2));
    float* hg     = (float*)alloc((size_t)XCDS * 2 * 2 * H_ * 4 * sizeof(float));  // 2 MB
    unsigned short* pre = (unsigned short*)alloc((size_t)16 * T_ * H_ * 4 * sizeof(unsigned short)); // 67 MB

    hipMemsetAsync(zbase, 0, (size_t)ZINTS * sizeof(int), stream);
    hipMemsetAsync(hg, 0, (size_t)XCDS * 2 * 2 * H_ * 4 * sizeof(float), stream);

    transpose_x<<<dim3(I_ / 128, 8, T_), dim3(128, 8), 0, stream>>>(x, xT2);

    hist_rows<<<(nnz_ih + 255) / 256, 256, 0, stream>>>(ih_rows, nnz_ih, ih_cnt);
    scan_rows<<<1, 64, 0, stream>>>(ih_cnt, ih_rp, H_);
    scatter_pack<<<(nnz_ih + 255) / 256, 256, 0, stream>>>(ih_rows, ih_cols, ih_vals, nnz_ih,
                                                           ih_rp, ih_cur, ih_pack);
    hist_rows<<<(nnz_hh + 255) / 256, 256, 0, stream>>>(hh_rows, nnz_hh, hh_cnt);
    scan_rows<<<1, 64, 0, stream>>>(hh_cnt, hh_rp, H_);
    scatter_pack<<<(nnz_hh + 255) / 256, 256, 0, stream>>>(hh_rows, hh_cols, hh_vals, nnz_hh,
                                                           hh_rp, hh_cur, hh_pack);

    precompute_ih<<<dim3(H_ / 32, 8), dim3(256), 0, stream>>>(xT2, ih_rp, ih_pack,
                                                              hh_bias, pre);

    void* kargs[] = {
        (void*)&hh_rp, (void*)&hh_pack,
        (void*)&pre,
        (void*)&hg,
        (void*)&regcnt, (void*)&barcnt, (void*)&bargen,
        (void*)&owncnt, (void*)&owngrp,
        (void*)&out,
    };
    hipLaunchCooperativeKernel((const void*)rnn_steps, dim3(RNN_BLOCKS), dim3(RNN_THREADS),
                               kargs, 0, stream);
}

// Round 7
// 1922.042 us; speedup vs baseline: 1.4722x; 1.0046x over previous
//
#include <hip/hip_runtime.h>
#include <hip/hip_cooperative_groups.h>
#include <math.h>

namespace cg = cooperative_groups;

#define B_ 64
#define T_ 128
#define I_ 1024
#define H_ 4096
#define XCDS 8

#define RNN_BLOCKS 256
#define RNN_THREADS 1024

#define MAXIT_IH 8    // 64 nnz/row registerized (Poisson(32)); tail fallback beyond

// ---------------- helpers ----------------
__device__ __forceinline__ unsigned short f2bf(float f) {
    unsigned int u = __float_as_uint(f);
    unsigned int r = (u + 0x7fffu + ((u >> 16) & 1u)) >> 16;
    return (unsigned short)r;
}

__device__ __forceinline__ void load4x16_sc0(const float* p0, const float* p1,
                                             const float* p2, const float* p3,
                                             float4& a, float4& b, float4& c, float4& d) {
    asm volatile(
        "global_load_dwordx4 %0, %4, off sc0\n\t"
        "global_load_dwordx4 %1, %5, off sc0\n\t"
        "global_load_dwordx4 %2, %6, off sc0\n\t"
        "global_load_dwordx4 %3, %7, off sc0\n\t"
        "s_waitcnt vmcnt(0)"
        : "=&v"(a), "=&v"(b), "=&v"(c), "=&v"(d)
        : "v"(p0), "v"(p1), "v"(p2), "v"(p3));
}

// ---------------- transpose x (B,T,I) -> xT2 (T, 8, I, 8) ----------------
__global__ void transpose_x(const float* __restrict__ x, float* __restrict__ xT2) {
    __shared__ float lds[8][129];
    int t  = blockIdx.z;
    int bg = blockIdx.y;
    int i0 = blockIdx.x * 128;
    int tx = threadIdx.x;   // 0..127
    int ty = threadIdx.y;   // 0..7
    int b = bg * 8 + ty;
    lds[ty][tx] = x[(size_t)b * T_ * I_ + (size_t)t * I_ + i0 + tx];
    __syncthreads();
    int n  = ty * 128 + tx;
    int ii = n >> 3;
    int bs = n & 7;
    xT2[(((size_t)t * 8 + bg) * I_ + i0 + ii) * 8 + bs] = lds[bs][ii];
}

// ---------------- CSR build ----------------
__global__ void hist_rows(const int* __restrict__ rows, int nnz, int* __restrict__ counts) {
    int k = blockIdx.x * blockDim.x + threadIdx.x;
    if (k < nnz) atomicAdd(&counts[rows[k]], 1);
}

__global__ void scan_rows(const int* __restrict__ counts, int* __restrict__ rp, int n) {
    int lane = threadIdx.x;      // 0..63
    int chunk = n / 64;
    int base = lane * chunk;
    int s = 0;
    for (int j = 0; j < chunk; ++j) s += counts[base + j];
    int pre = s;
    for (int off = 1; off < 64; off <<= 1) {
        int up = __shfl_up(pre, off, 64);
        if (lane >= off) pre += up;
    }
    int run = pre - s;
    for (int j = 0; j < chunk; ++j) { rp[base + j] = run; run += counts[base + j]; }
    if (lane == 63) rp[n] = run;
}

__global__ void scatter_pack(const int* __restrict__ rows, const int* __restrict__ cols,
                             const float* __restrict__ vals, int nnz,
                             const int* __restrict__ rp, int* __restrict__ cursor,
                             int2* __restrict__ pack) {
    int k = blockIdx.x * blockDim.x + threadIdx.x;
    if (k < nnz) {
        int r = rows[k];
        int pos = atomicAdd(&cursor[r], 1);
        pack[rp[r] + pos] = make_int2(cols[k], __float_as_int(vals[k]));
    }
}

// ---------------- bank-aware per-row reorder ----------------
// Round-robin interleave each row's nnz across (col & mask) buckets so that
// consecutive window slots hit distinct LDS bank groups. Output position of
// the j-th element of bucket b: sum_q min(cnt[q],j) + #{q<b : cnt[q]>j}.
// Sum-order change only (already nondeterministic from scatter_pack atomics).
__global__ void reorder_rows(const int* __restrict__ rp, const int2* __restrict__ pack,
                             int2* __restrict__ pack2, int mask) {
    int r = blockIdx.x * blockDim.x + threadIdx.x;
    if (r >= H_) return;
    int b0 = rp[r], e0 = rp[r + 1];
    int cnt[8];
    #pragma unroll
    for (int q = 0; q < 8; ++q) cnt[q] = 0;
    for (int k = b0; k < e0; ++k) cnt[pack[k].x & mask]++;
    int seen[8];
    #pragma unroll
    for (int q = 0; q < 8; ++q) seen[q] = 0;
    for (int k = b0; k < e0; ++k) {
        int2 pk = pack[k];
        int b = pk.x & mask;
        int j = seen[b]++;
        int pos = 0;
        for (int q = 0; q <= mask; ++q) {
            pos += min(cnt[q], j);
            if (q < b && cnt[q] > j) pos++;
        }
        pack2[b0 + pos] = pk;
    }
}

// ---------------- kernel P: pre[t] = W_ih * x_t + bias  (bf16 out) ----------------
// Round-3 proven form: one block per (4 row-groups, grp); t-loop inside. CSR
// slice registerized (t-invariant), x_t slice staged in LDS (32 KB), 1 rg/wave.
__global__ __launch_bounds__(256)
void precompute_ih(const float* __restrict__ xT2,
                   const int* __restrict__ rp, const int2* __restrict__ pack,
                   const float* __restrict__ bias,
                   unsigned short* __restrict__ pre) {
    __shared__ __align__(16) float xs[I_ * 8];   // 32 KB: x_t slice for this grp
    int grp  = blockIdx.y;
    int wave = threadIdx.x >> 6;                  // 0..3
    int lane = threadIdx.x & 63;
    int rs = lane >> 3;   // row within group
    int u  = lane & 7;    // position within window

    int g = blockIdx.x * 4 + wave;                // 0..511
    int r = g * 8 + rs;
    int hb = rp[r];
    int len = rp[r + 1] - hb;
    int lm = len;
    lm = max(lm, __shfl_xor(lm, 8));
    lm = max(lm, __shfl_xor(lm, 16));
    lm = max(lm, __shfl_xor(lm, 32));
    int lmax = __builtin_amdgcn_readfirstlane(lm);
    float bsv = bias[r];

    // registerize the CSR slice (t-invariant): byte offsets pre-shifted
    int   pcol[MAXIT_IH];
    float pval[MAXIT_IH];
    #pragma unroll
    for (int it = 0; it < MAXIT_IH; ++it) {
        int2 pk = make_int2(0, 0);
        if (it * 8 + u < len) pk = pack[hb + it * 8 + u];
        pcol[it] = pk.x << 5;                 // col * 8 floats * 4 B
        pval[it] = __int_as_float(pk.y);
    }

    for (int t = 0; t < T_; ++t) {
        const float* xt = xT2 + ((size_t)t * 8 + grp) * (I_ * 8);
        __syncthreads();    // prior step's reads of xs done
        {
            const float4* s = (const float4*)xt;
            float4* d = (float4*)xs;
            #pragma unroll
            for (int j = 0; j < 8; ++j)
                d[j * 256 + threadIdx.x] = s[j * 256 + threadIdx.x];
        }
        __syncthreads();    // xs ready

        float a[8];
        #pragma unroll
        for (int j = 0; j < 8; ++j) a[j] = 0.0f;

        // branchless registerized windows (padded lanes read xs[0], add +0.0)
        #pragma unroll
        for (int it = 0; it < MAXIT_IH; ++it) {
            const float* gp = (const float*)((const char*)xs + pcol[it]);
            float4 x0 = *(const float4*)gp;
            float4 x1 = *(const float4*)(gp + 4);
            float v = pval[it];
            a[0] += v * x0.x; a[1] += v * x0.y; a[2] += v * x0.z; a[3] += v * x0.w;
            a[4] += v * x1.x; a[5] += v * x1.y; a[6] += v * x1.z; a[7] += v * x1.w;
        }
        if (lmax > 8 * MAXIT_IH) {   // rare tail, same summation order
            int kk = hb + 8 * MAXIT_IH + u;
            for (int i = 8 * MAXIT_IH; i < lmax; i += 8, kk += 8) {
                int2 pk = make_int2(0, 0);
                if (i + u < len) pk = pack[kk];
                const float* gp = (const float*)((const char*)xs + ((size_t)pk.x << 5));
                float4 x0 = *(const float4*)gp;
                float4 x1 = *(const float4*)(gp + 4);
                float v = __int_as_float(pk.y);
                a[0] += v * x0.x; a[1] += v * x0.y; a[2] += v * x0.z; a[3] += v * x0.w;
                a[4] += v * x1.x; a[5] += v * x1.y; a[6] += v * x1.z; a[7] += v * x1.w;
            }
        }
        #pragma unroll
        for (int off = 1; off <= 4; off <<= 1) {
            #pragma unroll
            for (int j = 0; j < 8; ++j) a[j] += __shfl_xor(a[j], off);
        }
        float sel = (u == 0) ? a[0] : (u == 1) ? a[1] : (u == 2) ? a[2] : (u == 3) ? a[3]
                  : (u == 4) ? a[4] : (u == 5) ? a[5] : (u == 6) ? a[6] : a[7];
        float p = sel + bsv;
        int hf = u >> 2, cc = u & 3;
        pre[((size_t)(grp * 2 + hf) * T_ + t) * (H_ * 4) + (size_t)r * 4 + cc] = f2bf(p);
    }
}

// ---------------- kernel R: persistent XCD-local recurrence ----------------
// Round-0 proven body and launch config (256 blocks). Only delta vs round 3:
// bank-reordered hhpack input (data-only change).
// hg layout: hg[((grp*2 + parity)*2 + half) * (H_*4)]
__global__ __launch_bounds__(RNN_THREADS, 1)
void rnn_steps(const int* __restrict__ hhp, const int2* __restrict__ hhpack,
               const unsigned short* __restrict__ pre,
               float* __restrict__ hg,
               int* __restrict__ regcnt, int* __restrict__ barcnt, int* __restrict__ bargen,
               int* __restrict__ owncnt, int* __restrict__ owngrp,
               float* __restrict__ out) {
    cg::grid_group grid = cg::this_grid();
    __shared__ __align__(16) float sh[H_ * 4];   // 64 KB: h_prev, 4 batch cols of this half

    int tid = threadIdx.x;
    if (tid == 0) {
        int x;
        asm volatile("s_getreg_b32 %0, hwreg(HW_REG_XCC_ID)" : "=s"(x));
        x &= 7;
        int slot = __hip_atomic_fetch_add(&regcnt[x], 1, __ATOMIC_RELAXED,
                                          __HIP_MEMORY_SCOPE_AGENT);
        sh[0] = __int_as_float(x);
        sh[1] = __int_as_float(slot);
    }
    __syncthreads();
    int xcd  = __float_as_int(sh[0]);
    int slot = __float_as_int(sh[1]);
    grid.sync();

    if (blockIdx.x == 0 && tid == 0) {
        int list[XCDS]; int nz = 0;
        for (int j = 0; j < XCDS; ++j) {
            owncnt[j] = 0;
            if (__hip_atomic_load(&regcnt[j], __ATOMIC_RELAXED,
                                  __HIP_MEMORY_SCOPE_AGENT) > 0) list[nz++] = j;
        }
        int rr = 0;
        for (int j = 0; j < XCDS; ++j) {
            int present = __hip_atomic_load(&regcnt[j], __ATOMIC_RELAXED,
                                            __HIP_MEMORY_SCOPE_AGENT) > 0;
            int owner = present ? j : list[rr++ % nz];
            owngrp[owner * 8 + owncnt[owner]] = j;
            owncnt[owner] += 1;
        }
    }
    grid.sync();

    int nblk = __hip_atomic_load(&regcnt[xcd], __ATOMIC_RELAXED, __HIP_MEMORY_SCOPE_AGENT);
    int nown = owncnt[xcd];

    int wave = tid >> 6;
    int lane = tid & 63;
    int rs   = lane >> 3;
    int u    = lane & 7;

    // half assignment (robust to nblk==1)
    int hfbeg, hfend, mywave, nwh;
    if (nblk >= 2) {
        int hf = slot & 1;
        hfbeg = hf; hfend = hf + 1;
        int nhb = (hf == 0) ? ((nblk + 1) >> 1) : (nblk >> 1);
        mywave = (slot >> 1) * (RNN_THREADS / 64) + wave;
        nwh = nhb * (RNN_THREADS / 64);
    } else {
        hfbeg = 0; hfend = 2;
        mywave = wave; nwh = RNN_THREADS / 64;
    }

    int* bc = &barcnt[xcd * 32];
    int* bgen = &bargen[xcd * 32];

    for (int t = 0; t < T_; ++t) {
        for (int oi = 0; oi < nown; ++oi) {
            int grp = owngrp[xcd * 8 + oi];
            for (int hf = hfbeg; hf < hfend; ++hf) {
                const float* src = hg + (size_t)((grp * 2 + (t & 1)) * 2 + hf) * (H_ * 4);
                float*       dst = hg + (size_t)((grp * 2 + ((t + 1) & 1)) * 2 + hf) * (H_ * 4);

                // ---- fill sh with h_prev (sc0: bypass stale L1, hit local L2) ----
                __syncthreads();   // prior readers of sh are done
                {
                    float4 v0, v1, v2, v3;
                    const float* p0 = src + (size_t)(0 * 1024 + tid) * 4;
                    const float* p1 = src + (size_t)(1 * 1024 + tid) * 4;
                    const float* p2 = src + (size_t)(2 * 1024 + tid) * 4;
                    const float* p3 = src + (size_t)(3 * 1024 + tid) * 4;
                    load4x16_sc0(p0, p1, p2, p3, v0, v1, v2, v3);
                    float4* s4 = (float4*)sh;
                    s4[0 * 1024 + tid] = v0;
                    s4[1 * 1024 + tid] = v1;
                    s4[2 * 1024 + tid] = v2;
                    s4[3 * 1024 + tid] = v3;
                }
                __syncthreads();   // sh ready

                // ---- compute: hh SpMM rows + pre + tanh ----
                for (int g = mywave; g < H_ / 8; g += nwh) {
                    int r  = g * 8 + rs;
                    int hb = hhp[r], he = hhp[r + 1];
                    int len = he - hb;
                    int lmax = len;
                    lmax = max(lmax, __shfl_xor(lmax, 8));
                    lmax = max(lmax, __shfl_xor(lmax, 16));
                    lmax = max(lmax, __shfl_xor(lmax, 32));

                    float a0 = 0.f, a1 = 0.f, a2 = 0.f, a3 = 0.f;
                    int kk = hb + u;
                    for (int i = 0; i < lmax; i += 8, kk += 8) {
                        int2 pk = make_int2(0, 0);
                        if (i + u < len) pk = hhpack[kk];
                        float4 hv = ((const float4*)sh)[pk.x];
                        float v = __int_as_float(pk.y);
                        a0 += v * hv.x; a1 += v * hv.y; a2 += v * hv.z; a3 += v * hv.w;
                    }
                    #pragma unroll
                    for (int off = 1; off <= 4; off <<= 1) {
                        a0 += __shfl_xor(a0, off);
                        a1 += __shfl_xor(a1, off);
                        a2 += __shfl_xor(a2, off);
                        a3 += __shfl_xor(a3, off);
                    }
                    if (u < 4) {
                        float acc = (u == 0) ? a0 : (u == 1) ? a1 : (u == 2) ? a2 : a3;
                        float pv = __uint_as_float(
                            (unsigned int)pre[((size_t)(grp * 2 + hf) * T_ + t) * (H_ * 4) +
                                              (size_t)r * 4 + u] << 16);
                        float h = tanhf(acc + pv);
                        dst[(size_t)r * 4 + u] = h;
                        int b = grp * 8 + hf * 4 + u;
                        out[(size_t)b * T_ * H_ + (size_t)t * H_ + r] = h;
                    }
                }
            }
        }

        // ---- per-XCD barrier (no cache maintenance) ----
        __syncthreads();   // drains this block's h stores to L2 (vmcnt(0) before s_barrier)
        if (tid == 0) {
            asm volatile("s_waitcnt vmcnt(0)" ::: "memory");
            int target = t + 1;
            int old = __hip_atomic_fetch_add(bc, 1, __ATOMIC_RELAXED,
                                             __HIP_MEMORY_SCOPE_AGENT);
            if (old == nblk - 1) {
                __hip_atomic_store(bc, 0, __ATOMIC_RELAXED, __HIP_MEMORY_SCOPE_AGENT);
                __hip_atomic_store(bgen, target, __ATOMIC_RELAXED, __HIP_MEMORY_SCOPE_AGENT);
            } else {
                while (__hip_atomic_load(bgen, __ATOMIC_RELAXED,
                                         __HIP_MEMORY_SCOPE_AGENT) < target) {
                    __builtin_amdgcn_s_sleep(1);
                }
            }
        }
        __syncthreads();
    }
}

// ---------------- host launch ----------------
extern "C" void kernel_launch(void* const* d_in, const int* in_sizes, int n_in,
                              void* d_out, int out_size, void* d_ws, size_t ws_size,
                              hipStream_t stream) {
    const float* x       = (const float*)d_in[0];
    const float* ih_vals = (const float*)d_in[1];
    const float* hh_vals = (const float*)d_in[2];
    const float* hh_bias = (const float*)d_in[3];
    const int*   ih_rows = (const int*)d_in[4];
    const int*   ih_cols = (const int*)d_in[5];
    const int*   hh_rows = (const int*)d_in[6];
    const int*   hh_cols = (const int*)d_in[7];
    float* out = (float*)d_out;

    const int nnz_ih = in_sizes[1];
    const int nnz_hh = in_sizes[2];

    char* ws = (char*)d_ws;
    size_t off = 0;
    auto alloc = [&](size_t bytes) -> void* {
        off = (off + 255) & ~(size_t)255;
        void* p = ws + off;
        off += bytes;
        return p;
    };

    float* xT2   = (float*)alloc((size_t)T_ * 8 * I_ * 8 * sizeof(float));
    int*   ih_rp = (int*)  alloc((H_ + 1) * sizeof(int));
    int*   hh_rp = (int*)  alloc((H_ + 1) * sizeof(int));

    const int ZINTS = 4 * H_ + 64 + 8 * 32 + 8 * 32 + 8 + 64;
    int* zbase  = (int*)alloc((size_t)ZINTS * sizeof(int));
    int* ih_cnt = zbase;
    int* ih_cur = zbase + H_;
    int* hh_cnt = zbase + 2 * H_;
    int* hh_cur = zbase + 3 * H_;
    int* regcnt = zbase + 4 * H_;
    int* barcnt = regcnt + 64;
    int* bargen = barcnt + 8 * 32;
    int* owncnt = bargen + 8 * 32;
    int* owngrp = owncnt + 8;

    int2* ih_pack  = (int2*)alloc((size_t)nnz_ih * sizeof(int2));
    int2* hh_pack  = (int2*)alloc((size_t)nnz_hh * sizeof(int2));
    int2* ih_pack2 = (int2*)alloc((size_t)nnz_ih * sizeof(int2));
    int2* hh_pack2 = (int2*)alloc((size_t)nnz_hh * sizeof(int2));
    float* hg     = (float*)alloc((size_t)XCDS * 2 * 2 * H_ * 4 * sizeof(float));  // 2 MB
    unsigned short* pre = (unsigned short*)alloc((size_t)16 * T_ * H_ * 4 * sizeof(unsigned short)); // 67 MB

    hipMemsetAsync(zbase, 0, (size_t)ZINTS * sizeof(int), stream);
    hipMemsetAsync(hg, 0, (size_t)XCDS * 2 * 2 * H_ * 4 * sizeof(float), stream);

    transpose_x<<<dim3(I_ / 128, 8, T_), dim3(128, 8), 0, stream>>>(x, xT2);

    hist_rows<<<(nnz_ih + 255) / 256, 256, 0, stream>>>(ih_rows, nnz_ih, ih_cnt);
    scan_rows<<<1, 64, 0, stream>>>(ih_cnt, ih_rp, H_);
    scatter_pack<<<(nnz_ih + 255) / 256, 256, 0, stream>>>(ih_rows, ih_cols, ih_vals, nnz_ih,
                                                           ih_rp, ih_cur, ih_pack);
    hist_rows<<<(nnz_hh + 255) / 256, 256, 0, stream>>>(hh_rows, nnz_hh, hh_cnt);
    scan_rows<<<1, 64, 0, stream>>>(hh_cnt, hh_rp, H_);
    scatter_pack<<<(nnz_hh + 255) / 256, 256, 0, stream>>>(hh_rows, hh_cols, hh_vals, nnz_hh,
                                                           hh_rp, hh_cur, hh_pack);

    // bank-aware reorder: ih gathers 32 B/col (bank group col&3), hh 16 B/col (col&7)
    reorder_rows<<<(H_ + 255) / 256, 256, 0, stream>>>(ih_rp, ih_pack, ih_pack2, 3);
    reorder_rows<<<(H_ + 255) / 256, 256, 0, stream>>>(hh_rp, hh_pack, hh_pack2, 7);

    precompute_ih<<<dim3(H_ / 32, 8), dim3(256), 0, stream>>>(xT2, ih_rp, ih_pack2,
                                                              hh_bias, pre);

    void* kargs[] = {
        (void*)&hh_rp, (void*)&hh_pack2,
        (void*)&pre,
        (void*)&hg,
        (void*)&regcnt, (void*)&barcnt, (void*)&bargen,
        (void*)&owncnt, (void*)&owngrp,
        (void*)&out,
    };
    hipLaunchCooperativeKernel((const void*)rnn_steps, dim3(RNN_BLOCKS), dim3(RNN_THREADS),
                               kargs, 0, stream);
}

// Round 8
// 1614.058 us; speedup vs baseline: 1.7531x; 1.1908x over previous
//
#include <hip/hip_runtime.h>
#include <hip/hip_cooperative_groups.h>
#include <math.h>

namespace cg = cooperative_groups;

#define B_ 64
#define T_ 128
#define I_ 1024
#define H_ 4096
#define XCDS 8

#define RNN_BLOCKS 256
#define RNN_THREADS 1024

#define MAXIT_IH 8    // 64 nnz/row registerized (Poisson(32)); tail fallback beyond

// ---------------- helpers ----------------
__device__ __forceinline__ unsigned short f2bf(float f) {
    unsigned int u = __float_as_uint(f);
    unsigned int r = (u + 0x7fffu + ((u >> 16) & 1u)) >> 16;
    return (unsigned short)r;
}

__device__ __forceinline__ void load4x16_sc0(const float* p0, const float* p1,
                                             const float* p2, const float* p3,
                                             float4& a, float4& b, float4& c, float4& d) {
    asm volatile(
        "global_load_dwordx4 %0, %4, off sc0\n\t"
        "global_load_dwordx4 %1, %5, off sc0\n\t"
        "global_load_dwordx4 %2, %6, off sc0\n\t"
        "global_load_dwordx4 %3, %7, off sc0\n\t"
        "s_waitcnt vmcnt(0)"
        : "=&v"(a), "=&v"(b), "=&v"(c), "=&v"(d)
        : "v"(p0), "v"(p1), "v"(p2), "v"(p3));
}

// ---------------- transpose x (B,T,I) -> xT2 (T, 8, I, 8) ----------------
__global__ void transpose_x(const float* __restrict__ x, float* __restrict__ xT2) {
    __shared__ float lds[8][129];
    int t  = blockIdx.z;
    int bg = blockIdx.y;
    int i0 = blockIdx.x * 128;
    int tx = threadIdx.x;   // 0..127
    int ty = threadIdx.y;   // 0..7
    int b = bg * 8 + ty;
    lds[ty][tx] = x[(size_t)b * T_ * I_ + (size_t)t * I_ + i0 + tx];
    __syncthreads();
    int n  = ty * 128 + tx;
    int ii = n >> 3;
    int bs = n & 7;
    xT2[(((size_t)t * 8 + bg) * I_ + i0 + ii) * 8 + bs] = lds[bs][ii];
}

// ---------------- CSR build ----------------
__global__ void hist_rows(const int* __restrict__ rows, int nnz, int* __restrict__ counts) {
    int k = blockIdx.x * blockDim.x + threadIdx.x;
    if (k < nnz) atomicAdd(&counts[rows[k]], 1);
}

__global__ void scan_rows(const int* __restrict__ counts, int* __restrict__ rp, int n) {
    int lane = threadIdx.x;      // 0..63
    int chunk = n / 64;
    int base = lane * chunk;
    int s = 0;
    for (int j = 0; j < chunk; ++j) s += counts[base + j];
    int pre = s;
    for (int off = 1; off < 64; off <<= 1) {
        int up = __shfl_up(pre, off, 64);
        if (lane >= off) pre += up;
    }
    int run = pre - s;
    for (int j = 0; j < chunk; ++j) { rp[base + j] = run; run += counts[base + j]; }
    if (lane == 63) rp[n] = run;
}

__global__ void scatter_pack(const int* __restrict__ rows, const int* __restrict__ cols,
                             const float* __restrict__ vals, int nnz,
                             const int* __restrict__ rp, int* __restrict__ cursor,
                             int2* __restrict__ pack) {
    int k = blockIdx.x * blockDim.x + threadIdx.x;
    if (k < nnz) {
        int r = rows[k];
        int pos = atomicAdd(&cursor[r], 1);
        pack[rp[r] + pos] = make_int2(cols[k], __float_as_int(vals[k]));
    }
}

// ---------------- kernel P: pre[t] = W_ih * x_t + bias  (bf16 out) ----------------
// Round-3 proven form: one block per (4 row-groups, grp); t-loop inside. CSR
// slice registerized (t-invariant), x_t slice staged in LDS (32 KB), 1 rg/wave.
__global__ __launch_bounds__(256)
void precompute_ih(const float* __restrict__ xT2,
                   const int* __restrict__ rp, const int2* __restrict__ pack,
                   const float* __restrict__ bias,
                   unsigned short* __restrict__ pre) {
    __shared__ __align__(16) float xs[I_ * 8];   // 32 KB: x_t slice for this grp
    int grp  = blockIdx.y;
    int wave = threadIdx.x >> 6;                  // 0..3
    int lane = threadIdx.x & 63;
    int rs = lane >> 3;   // row within group
    int u  = lane & 7;    // position within window

    int g = blockIdx.x * 4 + wave;                // 0..511
    int r = g * 8 + rs;
    int hb = rp[r];
    int len = rp[r + 1] - hb;
    int lm = len;
    lm = max(lm, __shfl_xor(lm, 8));
    lm = max(lm, __shfl_xor(lm, 16));
    lm = max(lm, __shfl_xor(lm, 32));
    int lmax = __builtin_amdgcn_readfirstlane(lm);
    float bsv = bias[r];

    // registerize the CSR slice (t-invariant): byte offsets pre-shifted
    int   pcol[MAXIT_IH];
    float pval[MAXIT_IH];
    #pragma unroll
    for (int it = 0; it < MAXIT_IH; ++it) {
        int2 pk = make_int2(0, 0);
        if (it * 8 + u < len) pk = pack[hb + it * 8 + u];
        pcol[it] = pk.x << 5;                 // col * 8 floats * 4 B
        pval[it] = __int_as_float(pk.y);
    }

    for (int t = 0; t < T_; ++t) {
        const float* xt = xT2 + ((size_t)t * 8 + grp) * (I_ * 8);
        __syncthreads();    // prior step's reads of xs done
        {
            const float4* s = (const float4*)xt;
            float4* d = (float4*)xs;
            #pragma unroll
            for (int j = 0; j < 8; ++j)
                d[j * 256 + threadIdx.x] = s[j * 256 + threadIdx.x];
        }
        __syncthreads();    // xs ready

        float a[8];
        #pragma unroll
        for (int j = 0; j < 8; ++j) a[j] = 0.0f;

        // branchless registerized windows (padded lanes read xs[0], add +0.0)
        #pragma unroll
        for (int it = 0; it < MAXIT_IH; ++it) {
            const float* gp = (const float*)((const char*)xs + pcol[it]);
            float4 x0 = *(const float4*)gp;
            float4 x1 = *(const float4*)(gp + 4);
            float v = pval[it];
            a[0] += v * x0.x; a[1] += v * x0.y; a[2] += v * x0.z; a[3] += v * x0.w;
            a[4] += v * x1.x; a[5] += v * x1.y; a[6] += v * x1.z; a[7] += v * x1.w;
        }
        if (lmax > 8 * MAXIT_IH) {   // rare tail, same summation order
            int kk = hb + 8 * MAXIT_IH + u;
            for (int i = 8 * MAXIT_IH; i < lmax; i += 8, kk += 8) {
                int2 pk = make_int2(0, 0);
                if (i + u < len) pk = pack[kk];
                const float* gp = (const float*)((const char*)xs + ((size_t)pk.x << 5));
                float4 x0 = *(const float4*)gp;
                float4 x1 = *(const float4*)(gp + 4);
                float v = __int_as_float(pk.y);
                a[0] += v * x0.x; a[1] += v * x0.y; a[2] += v * x0.z; a[3] += v * x0.w;
                a[4] += v * x1.x; a[5] += v * x1.y; a[6] += v * x1.z; a[7] += v * x1.w;
            }
        }
        #pragma unroll
        for (int off = 1; off <= 4; off <<= 1) {
            #pragma unroll
            for (int j = 0; j < 8; ++j) a[j] += __shfl_xor(a[j], off);
        }
        float sel = (u == 0) ? a[0] : (u == 1) ? a[1] : (u == 2) ? a[2] : (u == 3) ? a[3]
                  : (u == 4) ? a[4] : (u == 5) ? a[5] : (u == 6) ? a[6] : a[7];
        float p = sel + bsv;
        int hf = u >> 2, cc = u & 3;
        pre[((size_t)(grp * 2 + hf) * T_ + t) * (H_ * 4) + (size_t)r * 4 + cc] = f2bf(p);
    }
}

// ---------------- kernel R: persistent XCD-local recurrence ----------------
// Round-0 proven structure. Deltas this round (latency-hiding only, same loads,
// same order, same arithmetic): (a) hhpack 1-deep software prefetch inside the
// window loop; (b) pre value loaded at row-group head instead of after reduce.
// hg layout: hg[((grp*2 + parity)*2 + half) * (H_*4)]
__global__ __launch_bounds__(RNN_THREADS, 1)
void rnn_steps(const int* __restrict__ hhp, const int2* __restrict__ hhpack,
               const unsigned short* __restrict__ pre,
               float* __restrict__ hg,
               int* __restrict__ regcnt, int* __restrict__ barcnt, int* __restrict__ bargen,
               int* __restrict__ owncnt, int* __restrict__ owngrp,
               float* __restrict__ out) {
    cg::grid_group grid = cg::this_grid();
    __shared__ __align__(16) float sh[H_ * 4];   // 64 KB: h_prev, 4 batch cols of this half

    int tid = threadIdx.x;
    if (tid == 0) {
        int x;
        asm volatile("s_getreg_b32 %0, hwreg(HW_REG_XCC_ID)" : "=s"(x));
        x &= 7;
        int slot = __hip_atomic_fetch_add(&regcnt[x], 1, __ATOMIC_RELAXED,
                                          __HIP_MEMORY_SCOPE_AGENT);
        sh[0] = __int_as_float(x);
        sh[1] = __int_as_float(slot);
    }
    __syncthreads();
    int xcd  = __float_as_int(sh[0]);
    int slot = __float_as_int(sh[1]);
    grid.sync();

    if (blockIdx.x == 0 && tid == 0) {
        int list[XCDS]; int nz = 0;
        for (int j = 0; j < XCDS; ++j) {
            owncnt[j] = 0;
            if (__hip_atomic_load(&regcnt[j], __ATOMIC_RELAXED,
                                  __HIP_MEMORY_SCOPE_AGENT) > 0) list[nz++] = j;
        }
        int rr = 0;
        for (int j = 0; j < XCDS; ++j) {
            int present = __hip_atomic_load(&regcnt[j], __ATOMIC_RELAXED,
                                            __HIP_MEMORY_SCOPE_AGENT) > 0;
            int owner = present ? j : list[rr++ % nz];
            owngrp[owner * 8 + owncnt[owner]] = j;
            owncnt[owner] += 1;
        }
    }
    grid.sync();

    int nblk = __hip_atomic_load(&regcnt[xcd], __ATOMIC_RELAXED, __HIP_MEMORY_SCOPE_AGENT);
    int nown = owncnt[xcd];

    int wave = tid >> 6;
    int lane = tid & 63;
    int rs   = lane >> 3;
    int u    = lane & 7;

    // half assignment (robust to nblk==1)
    int hfbeg, hfend, mywave, nwh;
    if (nblk >= 2) {
        int hf = slot & 1;
        hfbeg = hf; hfend = hf + 1;
        int nhb = (hf == 0) ? ((nblk + 1) >> 1) : (nblk >> 1);
        mywave = (slot >> 1) * (RNN_THREADS / 64) + wave;
        nwh = nhb * (RNN_THREADS / 64);
    } else {
        hfbeg = 0; hfend = 2;
        mywave = wave; nwh = RNN_THREADS / 64;
    }

    int* bc = &barcnt[xcd * 32];
    int* bgen = &bargen[xcd * 32];

    for (int t = 0; t < T_; ++t) {
        for (int oi = 0; oi < nown; ++oi) {
            int grp = owngrp[xcd * 8 + oi];
            for (int hf = hfbeg; hf < hfend; ++hf) {
                const float* src = hg + (size_t)((grp * 2 + (t & 1)) * 2 + hf) * (H_ * 4);
                float*       dst = hg + (size_t)((grp * 2 + ((t + 1) & 1)) * 2 + hf) * (H_ * 4);

                // ---- fill sh with h_prev (sc0: bypass stale L1, hit local L2) ----
                __syncthreads();   // prior readers of sh are done
                {
                    float4 v0, v1, v2, v3;
                    const float* p0 = src + (size_t)(0 * 1024 + tid) * 4;
                    const float* p1 = src + (size_t)(1 * 1024 + tid) * 4;
                    const float* p2 = src + (size_t)(2 * 1024 + tid) * 4;
                    const float* p3 = src + (size_t)(3 * 1024 + tid) * 4;
                    load4x16_sc0(p0, p1, p2, p3, v0, v1, v2, v3);
                    float4* s4 = (float4*)sh;
                    s4[0 * 1024 + tid] = v0;
                    s4[1 * 1024 + tid] = v1;
                    s4[2 * 1024 + tid] = v2;
                    s4[3 * 1024 + tid] = v3;
                }
                __syncthreads();   // sh ready

                // ---- compute: hh SpMM rows + pre + tanh ----
                for (int g = mywave; g < H_ / 8; g += nwh) {
                    int r  = g * 8 + rs;
                    int hb = hhp[r], he = hhp[r + 1];
                    int len = he - hb;
                    int lmax = len;
                    lmax = max(lmax, __shfl_xor(lmax, 8));
                    lmax = max(lmax, __shfl_xor(lmax, 16));
                    lmax = max(lmax, __shfl_xor(lmax, 32));

                    // early pre load (u<8 index safe; consumed after reduce)
                    unsigned short pus =
                        pre[((size_t)(grp * 2 + hf) * T_ + t) * (H_ * 4) +
                            (size_t)r * 4 + u];

                    float a0 = 0.f, a1 = 0.f, a2 = 0.f, a3 = 0.f;
                    int kk = hb + u;
                    int2 pk = make_int2(0, 0);
                    if (u < len) pk = hhpack[kk];
                    for (int i = 0; i < lmax; i += 8) {
                        kk += 8;
                        int2 pkn = make_int2(0, 0);
                        if (i + 8 + u < len) pkn = hhpack[kk];   // next-window prefetch
                        float4 hv = ((const float4*)sh)[pk.x];
                        float v = __int_as_float(pk.y);
                        a0 += v * hv.x; a1 += v * hv.y; a2 += v * hv.z; a3 += v * hv.w;
                        pk = pkn;
                    }
                    #pragma unroll
                    for (int off = 1; off <= 4; off <<= 1) {
                        a0 += __shfl_xor(a0, off);
                        a1 += __shfl_xor(a1, off);
                        a2 += __shfl_xor(a2, off);
                        a3 += __shfl_xor(a3, off);
                    }
                    if (u < 4) {
                        float acc = (u == 0) ? a0 : (u == 1) ? a1 : (u == 2) ? a2 : a3;
                        float pv = __uint_as_float((unsigned int)pus << 16);
                        float h = tanhf(acc + pv);
                        dst[(size_t)r * 4 + u] = h;
                        int b = grp * 8 + hf * 4 + u;
                        out[(size_t)b * T_ * H_ + (size_t)t * H_ + r] = h;
                    }
                }
            }
        }

        // ---- per-XCD barrier (no cache maintenance) ----
        __syncthreads();   // drains this block's h stores to L2 (vmcnt(0) before s_barrier)
        if (tid == 0) {
            asm volatile("s_waitcnt vmcnt(0)" ::: "memory");
            int target = t + 1;
            int old = __hip_atomic_fetch_add(bc, 1, __ATOMIC_RELAXED,
                                             __HIP_MEMORY_SCOPE_AGENT);
            if (old == nblk - 1) {
                __hip_atomic_store(bc, 0, __ATOMIC_RELAXED, __HIP_MEMORY_SCOPE_AGENT);
                __hip_atomic_store(bgen, target, __ATOMIC_RELAXED, __HIP_MEMORY_SCOPE_AGENT);
            } else {
                while (__hip_atomic_load(bgen, __ATOMIC_RELAXED,
                                         __HIP_MEMORY_SCOPE_AGENT) < target) {
                    __builtin_amdgcn_s_sleep(1);
                }
            }
        }
        __syncthreads();
    }
}

// ---------------- host launch ----------------
extern "C" void kernel_launch(void* const* d_in, const int* in_sizes, int n_in,
                              void* d_out, int out_size, void* d_ws, size_t ws_size,
                              hipStream_t stream) {
    const float* x       = (const float*)d_in[0];
    const float* ih_vals = (const float*)d_in[1];
    const float* hh_vals = (const float*)d_in[2];
    const float* hh_bias = (const float*)d_in[3];
    const int*   ih_rows = (const int*)d_in[4];
    const int*   ih_cols = (const int*)d_in[5];
    const int*   hh_rows = (const int*)d_in[6];
    const int*   hh_cols = (const int*)d_in[7];
    float* out = (float*)d_out;

    const int nnz_ih = in_sizes[1];
    const int nnz_hh = in_sizes[2];

    char* ws = (char*)d_ws;
    size_t off = 0;
    auto alloc = [&](size_t bytes) -> void* {
        off = (off + 255) & ~(size_t)255;
        void* p = ws + off;
        off += bytes;
        return p;
    };

    float* xT2   = (float*)alloc((size_t)T_ * 8 * I_ * 8 * sizeof(float));
    int*   ih_rp = (int*)  alloc((H_ + 1) * sizeof(int));
    int*   hh_rp = (int*)  alloc((H_ + 1) * sizeof(int));

    const int ZINTS = 4 * H_ + 64 + 8 * 32 + 8 * 32 + 8 + 64;
    int* zbase  = (int*)alloc((size_t)ZINTS * sizeof(int));
    int* ih_cnt = zbase;
    int* ih_cur = zbase + H_;
    int* hh_cnt = zbase + 2 * H_;
    int* hh_cur = zbase + 3 * H_;
    int* regcnt = zbase + 4 * H_;
    int* barcnt = regcnt + 64;
    int* bargen = barcnt + 8 * 32;
    int* owncnt = bargen + 8 * 32;
    int* owngrp = owncnt + 8;

    int2* ih_pack = (int2*)alloc((size_t)nnz_ih * sizeof(int2));
    int2* hh_pack = (int2*)alloc((size_t)nnz_hh * sizeof(int2));
    float* hg     = (float*)alloc((size_t)XCDS * 2 * 2 * H_ * 4 * sizeof(float));  // 2 MB
    unsigned short* pre = (unsigned short*)alloc((size_t)16 * T_ * H_ * 4 * sizeof(unsigned short)); // 67 MB

    hipMemsetAsync(zbase, 0, (size_t)ZINTS * sizeof(int), stream);
    hipMemsetAsync(hg, 0, (size_t)XCDS * 2 * 2 * H_ * 4 * sizeof(float), stream);

    transpose_x<<<dim3(I_ / 128, 8, T_), dim3(128, 8), 0, stream>>>(x, xT2);

    hist_rows<<<(nnz_ih + 255) / 256, 256, 0, stream>>>(ih_rows, nnz_ih, ih_cnt);
    scan_rows<<<1, 64, 0, stream>>>(ih_cnt, ih_rp, H_);
    scatter_pack<<<(nnz_ih + 255) / 256, 256, 0, stream>>>(ih_rows, ih_cols, ih_vals, nnz_ih,
                                                           ih_rp, ih_cur, ih_pack);
    hist_rows<<<(nnz_hh + 255) / 256, 256, 0, stream>>>(hh_rows, nnz_hh, hh_cnt);
    scan_rows<<<1, 64, 0, stream>>>(hh_cnt, hh_rp, H_);
    scatter_pack<<<(nnz_hh + 255) / 256, 256, 0, stream>>>(hh_rows, hh_cols, hh_vals, nnz_hh,
                                                           hh_rp, hh_cur, hh_pack);

    precompute_ih<<<dim3(H_ / 32, 8), dim3(256), 0, stream>>>(xT2, ih_rp, ih_pack,
                                                              hh_bias, pre);

    void* kargs[] = {
        (void*)&hh_rp, (void*)&hh_pack,
        (void*)&pre,
        (void*)&hg,
        (void*)&regcnt, (void*)&barcnt, (void*)&bargen,
        (void*)&owncnt, (void*)&owngrp,
        (void*)&out,
    };
    hipLaunchCooperativeKernel((const void*)rnn_steps, dim3(RNN_BLOCKS), dim3(RNN_THREADS),
                               kargs, 0, stream);
}

// Round 9
// 1610.460 us; speedup vs baseline: 1.7571x; 1.0022x over previous
//
#include <hip/hip_runtime.h>
#include <hip/hip_cooperative_groups.h>
#include <math.h>

namespace cg = cooperative_groups;

#define B_ 64
#define T_ 128
#define I_ 1024
#define H_ 4096
#define XCDS 8

#define RNN_BLOCKS 256
#define RNN_THREADS 1024

#define MAXIT_IH 8    // 64 nnz/row registerized (Poisson(32)); tail fallback beyond

// ---------------- helpers ----------------
__device__ __forceinline__ unsigned short f2bf(float f) {
    unsigned int u = __float_as_uint(f);
    unsigned int r = (u + 0x7fffu + ((u >> 16) & 1u)) >> 16;
    return (unsigned short)r;
}

__device__ __forceinline__ void load4x16_sc0(const float* p0, const float* p1,
                                             const float* p2, const float* p3,
                                             float4& a, float4& b, float4& c, float4& d) {
    asm volatile(
        "global_load_dwordx4 %0, %4, off sc0\n\t"
        "global_load_dwordx4 %1, %5, off sc0\n\t"
        "global_load_dwordx4 %2, %6, off sc0\n\t"
        "global_load_dwordx4 %3, %7, off sc0\n\t"
        "s_waitcnt vmcnt(0)"
        : "=&v"(a), "=&v"(b), "=&v"(c), "=&v"(d)
        : "v"(p0), "v"(p1), "v"(p2), "v"(p3));
}

// ---------------- transpose x (B,T,I) -> xT2 (T, 8, I, 8) ----------------
__global__ void transpose_x(const float* __restrict__ x, float* __restrict__ xT2) {
    __shared__ float lds[8][129];
    int t  = blockIdx.z;
    int bg = blockIdx.y;
    int i0 = blockIdx.x * 128;
    int tx = threadIdx.x;   // 0..127
    int ty = threadIdx.y;   // 0..7
    int b = bg * 8 + ty;
    lds[ty][tx] = x[(size_t)b * T_ * I_ + (size_t)t * I_ + i0 + tx];
    __syncthreads();
    int n  = ty * 128 + tx;
    int ii = n >> 3;
    int bs = n & 7;
    xT2[(((size_t)t * 8 + bg) * I_ + i0 + ii) * 8 + bs] = lds[bs][ii];
}

// ---------------- CSR build ----------------
__global__ void hist_rows(const int* __restrict__ rows, int nnz, int* __restrict__ counts) {
    int k = blockIdx.x * blockDim.x + threadIdx.x;
    if (k < nnz) atomicAdd(&counts[rows[k]], 1);
}

__global__ void scan_rows(const int* __restrict__ counts, int* __restrict__ rp, int n) {
    int lane = threadIdx.x;      // 0..63
    int chunk = n / 64;
    int base = lane * chunk;
    int s = 0;
    for (int j = 0; j < chunk; ++j) s += counts[base + j];
    int pre = s;
    for (int off = 1; off < 64; off <<= 1) {
        int up = __shfl_up(pre, off, 64);
        if (lane >= off) pre += up;
    }
    int run = pre - s;
    for (int j = 0; j < chunk; ++j) { rp[base + j] = run; run += counts[base + j]; }
    if (lane == 63) rp[n] = run;
}

__global__ void scatter_pack(const int* __restrict__ rows, const int* __restrict__ cols,
                             const float* __restrict__ vals, int nnz,
                             const int* __restrict__ rp, int* __restrict__ cursor,
                             int2* __restrict__ pack) {
    int k = blockIdx.x * blockDim.x + threadIdx.x;
    if (k < nnz) {
        int r = rows[k];
        int pos = atomicAdd(&cursor[r], 1);
        pack[rp[r] + pos] = make_int2(cols[k], __float_as_int(vals[k]));
    }
}

// ---------------- kernel P: pre[t] = W_ih * x_t + bias  (bf16 out) ----------------
// Round-3 structure, new geometry: 1024-thread blocks (16 waves share one x_t
// staging -> 4x less duplicated L2 traffic), grid (32, 8) = 1 block/CU.
// Each wave still owns exactly 1 row-group; CSR slice registerized (t-invariant).
__global__ __launch_bounds__(1024)
void precompute_ih(const float* __restrict__ xT2,
                   const int* __restrict__ rp, const int2* __restrict__ pack,
                   const float* __restrict__ bias,
                   unsigned short* __restrict__ pre) {
    __shared__ __align__(16) float xs[I_ * 8];   // 32 KB: x_t slice for this grp
    int grp  = blockIdx.y;
    int wave = threadIdx.x >> 6;                  // 0..15
    int lane = threadIdx.x & 63;
    int rs = lane >> 3;   // row within group
    int u  = lane & 7;    // position within window

    int g = blockIdx.x * 16 + wave;               // 0..511
    int r = g * 8 + rs;
    int hb = rp[r];
    int len = rp[r + 1] - hb;
    int lm = len;
    lm = max(lm, __shfl_xor(lm, 8));
    lm = max(lm, __shfl_xor(lm, 16));
    lm = max(lm, __shfl_xor(lm, 32));
    int lmax = __builtin_amdgcn_readfirstlane(lm);
    float bsv = bias[r];

    // registerize the CSR slice (t-invariant): byte offsets pre-shifted
    int   pcol[MAXIT_IH];
    float pval[MAXIT_IH];
    #pragma unroll
    for (int it = 0; it < MAXIT_IH; ++it) {
        int2 pk = make_int2(0, 0);
        if (it * 8 + u < len) pk = pack[hb + it * 8 + u];
        pcol[it] = pk.x << 5;                 // col * 8 floats * 4 B
        pval[it] = __int_as_float(pk.y);
    }

    for (int t = 0; t < T_; ++t) {
        const float* xt = xT2 + ((size_t)t * 8 + grp) * (I_ * 8);
        __syncthreads();    // prior step's reads of xs done
        {
            const float4* s = (const float4*)xt;
            float4* d = (float4*)xs;
            d[threadIdx.x]        = s[threadIdx.x];          // 2048 float4 = 32 KB
            d[1024 + threadIdx.x] = s[1024 + threadIdx.x];
        }
        __syncthreads();    // xs ready

        float a[8];
        #pragma unroll
        for (int j = 0; j < 8; ++j) a[j] = 0.0f;

        // branchless registerized windows (padded lanes read xs[0], add +0.0)
        #pragma unroll
        for (int it = 0; it < MAXIT_IH; ++it) {
            const float* gp = (const float*)((const char*)xs + pcol[it]);
            float4 x0 = *(const float4*)gp;
            float4 x1 = *(const float4*)(gp + 4);
            float v = pval[it];
            a[0] += v * x0.x; a[1] += v * x0.y; a[2] += v * x0.z; a[3] += v * x0.w;
            a[4] += v * x1.x; a[5] += v * x1.y; a[6] += v * x1.z; a[7] += v * x1.w;
        }
        if (lmax > 8 * MAXIT_IH) {   // rare tail, same summation order
            int kk = hb + 8 * MAXIT_IH + u;
            for (int i = 8 * MAXIT_IH; i < lmax; i += 8, kk += 8) {
                int2 pk = make_int2(0, 0);
                if (i + u < len) pk = pack[kk];
                const float* gp = (const float*)((const char*)xs + ((size_t)pk.x << 5));
                float4 x0 = *(const float4*)gp;
                float4 x1 = *(const float4*)(gp + 4);
                float v = __int_as_float(pk.y);
                a[0] += v * x0.x; a[1] += v * x0.y; a[2] += v * x0.z; a[3] += v * x0.w;
                a[4] += v * x1.x; a[5] += v * x1.y; a[6] += v * x1.z; a[7] += v * x1.w;
            }
        }
        #pragma unroll
        for (int off = 1; off <= 4; off <<= 1) {
            #pragma unroll
            for (int j = 0; j < 8; ++j) a[j] += __shfl_xor(a[j], off);
        }
        float sel = (u == 0) ? a[0] : (u == 1) ? a[1] : (u == 2) ? a[2] : (u == 3) ? a[3]
                  : (u == 4) ? a[4] : (u == 5) ? a[5] : (u == 6) ? a[6] : a[7];
        float p = sel + bsv;
        int hf = u >> 2, cc = u & 3;
        pre[((size_t)(grp * 2 + hf) * T_ + t) * (H_ * 4) + (size_t)r * 4 + cc] = f2bf(p);
    }
}

// ---------------- kernel R: persistent XCD-local recurrence ----------------
// Round-0 proven structure + round-8 proven prefetch, deepened: 2-stage pipeline
// (pack 2-deep, LDS gather 1-deep). Same loads, same guards, same FMA order.
// hg layout: hg[((grp*2 + parity)*2 + half) * (H_*4)]
__global__ __launch_bounds__(RNN_THREADS, 1)
void rnn_steps(const int* __restrict__ hhp, const int2* __restrict__ hhpack,
               const unsigned short* __restrict__ pre,
               float* __restrict__ hg,
               int* __restrict__ regcnt, int* __restrict__ barcnt, int* __restrict__ bargen,
               int* __restrict__ owncnt, int* __restrict__ owngrp,
               float* __restrict__ out) {
    cg::grid_group grid = cg::this_grid();
    __shared__ __align__(16) float sh[H_ * 4];   // 64 KB: h_prev, 4 batch cols of this half

    int tid = threadIdx.x;
    if (tid == 0) {
        int x;
        asm volatile("s_getreg_b32 %0, hwreg(HW_REG_XCC_ID)" : "=s"(x));
        x &= 7;
        int slot = __hip_atomic_fetch_add(&regcnt[x], 1, __ATOMIC_RELAXED,
                                          __HIP_MEMORY_SCOPE_AGENT);
        sh[0] = __int_as_float(x);
        sh[1] = __int_as_float(slot);
    }
    __syncthreads();
    int xcd  = __float_as_int(sh[0]);
    int slot = __float_as_int(sh[1]);
    grid.sync();

    if (blockIdx.x == 0 && tid == 0) {
        int list[XCDS]; int nz = 0;
        for (int j = 0; j < XCDS; ++j) {
            owncnt[j] = 0;
            if (__hip_atomic_load(&regcnt[j], __ATOMIC_RELAXED,
                                  __HIP_MEMORY_SCOPE_AGENT) > 0) list[nz++] = j;
        }
        int rr = 0;
        for (int j = 0; j < XCDS; ++j) {
            int present = __hip_atomic_load(&regcnt[j], __ATOMIC_RELAXED,
                                            __HIP_MEMORY_SCOPE_AGENT) > 0;
            int owner = present ? j : list[rr++ % nz];
            owngrp[owner * 8 + owncnt[owner]] = j;
            owncnt[owner] += 1;
        }
    }
    grid.sync();

    int nblk = __hip_atomic_load(&regcnt[xcd], __ATOMIC_RELAXED, __HIP_MEMORY_SCOPE_AGENT);
    int nown = owncnt[xcd];

    int wave = tid >> 6;
    int lane = tid & 63;
    int rs   = lane >> 3;
    int u    = lane & 7;

    // half assignment (robust to nblk==1)
    int hfbeg, hfend, mywave, nwh;
    if (nblk >= 2) {
        int hf = slot & 1;
        hfbeg = hf; hfend = hf + 1;
        int nhb = (hf == 0) ? ((nblk + 1) >> 1) : (nblk >> 1);
        mywave = (slot >> 1) * (RNN_THREADS / 64) + wave;
        nwh = nhb * (RNN_THREADS / 64);
    } else {
        hfbeg = 0; hfend = 2;
        mywave = wave; nwh = RNN_THREADS / 64;
    }

    int* bc = &barcnt[xcd * 32];
    int* bgen = &bargen[xcd * 32];

    for (int t = 0; t < T_; ++t) {
        for (int oi = 0; oi < nown; ++oi) {
            int grp = owngrp[xcd * 8 + oi];
            for (int hf = hfbeg; hf < hfend; ++hf) {
                const float* src = hg + (size_t)((grp * 2 + (t & 1)) * 2 + hf) * (H_ * 4);
                float*       dst = hg + (size_t)((grp * 2 + ((t + 1) & 1)) * 2 + hf) * (H_ * 4);

                // ---- fill sh with h_prev (sc0: bypass stale L1, hit local L2) ----
                __syncthreads();   // prior readers of sh are done
                {
                    float4 v0, v1, v2, v3;
                    const float* p0 = src + (size_t)(0 * 1024 + tid) * 4;
                    const float* p1 = src + (size_t)(1 * 1024 + tid) * 4;
                    const float* p2 = src + (size_t)(2 * 1024 + tid) * 4;
                    const float* p3 = src + (size_t)(3 * 1024 + tid) * 4;
                    load4x16_sc0(p0, p1, p2, p3, v0, v1, v2, v3);
                    float4* s4 = (float4*)sh;
                    s4[0 * 1024 + tid] = v0;
                    s4[1 * 1024 + tid] = v1;
                    s4[2 * 1024 + tid] = v2;
                    s4[3 * 1024 + tid] = v3;
                }
                __syncthreads();   // sh ready

                // ---- compute: hh SpMM rows + pre + tanh ----
                for (int g = mywave; g < H_ / 8; g += nwh) {
                    int r  = g * 8 + rs;
                    int hb = hhp[r], he = hhp[r + 1];
                    int len = he - hb;
                    int lmax = len;
                    lmax = max(lmax, __shfl_xor(lmax, 8));
                    lmax = max(lmax, __shfl_xor(lmax, 16));
                    lmax = max(lmax, __shfl_xor(lmax, 32));
                    int W = (lmax + 7) >> 3;   // number of windows

                    // early pre load (u<8 index safe; consumed after reduce)
                    unsigned short pus =
                        pre[((size_t)(grp * 2 + hf) * T_ + t) * (H_ * 4) +
                            (size_t)r * 4 + u];

                    // 2-stage pipeline: pack 2-deep, LDS gather 1-deep
                    float a0 = 0.f, a1 = 0.f, a2 = 0.f, a3 = 0.f;
                    int2 pkA = make_int2(0, 0), pkB = make_int2(0, 0);
                    if (u < len)     pkA = hhpack[hb + u];
                    if (8 + u < len) pkB = hhpack[hb + 8 + u];
                    float4 hvA = ((const float4*)sh)[pkA.x];
                    int kk = hb + 16 + u;
                    for (int w = 0; w < W; ++w, kk += 8) {
                        int2 pkC = make_int2(0, 0);
                        if (w * 8 + 16 + u < len) pkC = hhpack[kk];
                        float4 hvB = ((const float4*)sh)[pkB.x];
                        float v = __int_as_float(pkA.y);
                        a0 += v * hvA.x; a1 += v * hvA.y; a2 += v * hvA.z; a3 += v * hvA.w;
                        pkA = pkB; pkB = pkC; hvA = hvB;
                    }
                    #pragma unroll
                    for (int off = 1; off <= 4; off <<= 1) {
                        a0 += __shfl_xor(a0, off);
                        a1 += __shfl_xor(a1, off);
                        a2 += __shfl_xor(a2, off);
                        a3 += __shfl_xor(a3, off);
                    }
                    if (u < 4) {
                        float acc = (u == 0) ? a0 : (u == 1) ? a1 : (u == 2) ? a2 : a3;
                        float pv = __uint_as_float((unsigned int)pus << 16);
                        float h = tanhf(acc + pv);
                        dst[(size_t)r * 4 + u] = h;
                        int b = grp * 8 + hf * 4 + u;
                        out[(size_t)b * T_ * H_ + (size_t)t * H_ + r] = h;
                    }
                }
            }
        }

        // ---- per-XCD barrier (no cache maintenance) ----
        __syncthreads();   // drains this block's h stores to L2 (vmcnt(0) before s_barrier)
        if (tid == 0) {
            asm volatile("s_waitcnt vmcnt(0)" ::: "memory");
            int target = t + 1;
            int old = __hip_atomic_fetch_add(bc, 1, __ATOMIC_RELAXED,
                                             __HIP_MEMORY_SCOPE_AGENT);
            if (old == nblk - 1) {
                __hip_atomic_store(bc, 0, __ATOMIC_RELAXED, __HIP_MEMORY_SCOPE_AGENT);
                __hip_atomic_store(bgen, target, __ATOMIC_RELAXED, __HIP_MEMORY_SCOPE_AGENT);
            } else {
                while (__hip_atomic_load(bgen, __ATOMIC_RELAXED,
                                         __HIP_MEMORY_SCOPE_AGENT) < target) {
                    __builtin_amdgcn_s_sleep(1);
                }
            }
        }
        __syncthreads();
    }
}

// ---------------- host launch ----------------
extern "C" void kernel_launch(void* const* d_in, const int* in_sizes, int n_in,
                              void* d_out, int out_size, void* d_ws, size_t ws_size,
                              hipStream_t stream) {
    const float* x       = (const float*)d_in[0];
    const float* ih_vals = (const float*)d_in[1];
    const float* hh_vals = (const float*)d_in[2];
    const float* hh_bias = (const float*)d_in[3];
    const int*   ih_rows = (const int*)d_in[4];
    const int*   ih_cols = (const int*)d_in[5];
    const int*   hh_rows = (const int*)d_in[6];
    const int*   hh_cols = (const int*)d_in[7];
    float* out = (float*)d_out;

    const int nnz_ih = in_sizes[1];
    const int nnz_hh = in_sizes[2];

    char* ws = (char*)d_ws;
    size_t off = 0;
    auto alloc = [&](size_t bytes) -> void* {
        off = (off + 255) & ~(size_t)255;
        void* p = ws + off;
        off += bytes;
        return p;
    };

    float* xT2   = (float*)alloc((size_t)T_ * 8 * I_ * 8 * sizeof(float));
    int*   ih_rp = (int*)  alloc((H_ + 1) * sizeof(int));
    int*   hh_rp = (int*)  alloc((H_ + 1) * sizeof(int));

    const int ZINTS = 4 * H_ + 64 + 8 * 32 + 8 * 32 + 8 + 64;
    int* zbase  = (int*)alloc((size_t)ZINTS * sizeof(int));
    int* ih_cnt = zbase;
    int* ih_cur = zbase + H_;
    int* hh_cnt = zbase + 2 * H_;
    int* hh_cur = zbase + 3 * H_;
    int* regcnt = zbase + 4 * H_;
    int* barcnt = regcnt + 64;
    int* bargen = barcnt + 8 * 32;
    int* owncnt = bargen + 8 * 32;
    int* owngrp = owncnt + 8;

    int2* ih_pack = (int2*)alloc((size_t)nnz_ih * sizeof(int2));
    int2* hh_pack = (int2*)alloc((size_t)nnz_hh * sizeof(int2));
    float* hg     = (float*)alloc((size_t)XCDS * 2 * 2 * H_ * 4 * sizeof(float));  // 2 MB
    unsigned short* pre = (unsigned short*)alloc((size_t)16 * T_ * H_ * 4 * sizeof(unsigned short)); // 67 MB

    hipMemsetAsync(zbase, 0, (size_t)ZINTS * sizeof(int), stream);
    hipMemsetAsync(hg, 0, (size_t)XCDS * 2 * 2 * H_ * 4 * sizeof(float), stream);

    transpose_x<<<dim3(I_ / 128, 8, T_), dim3(128, 8), 0, stream>>>(x, xT2);

    hist_rows<<<(nnz_ih + 255) / 256, 256, 0, stream>>>(ih_rows, nnz_ih, ih_cnt);
    scan_rows<<<1, 64, 0, stream>>>(ih_cnt, ih_rp, H_);
    scatter_pack<<<(nnz_ih + 255) / 256, 256, 0, stream>>>(ih_rows, ih_cols, ih_vals, nnz_ih,
                                                           ih_rp, ih_cur, ih_pack);
    hist_rows<<<(nnz_hh + 255) / 256, 256, 0, stream>>>(hh_rows, nnz_hh, hh_cnt);
    scan_rows<<<1, 64, 0, stream>>>(hh_cnt, hh_rp, H_);
    scatter_pack<<<(nnz_hh + 255) / 256, 256, 0, stream>>>(hh_rows, hh_cols, hh_vals, nnz_hh,
                                                           hh_rp, hh_cur, hh_pack);

    precompute_ih<<<dim3(H_ / 8 / 16, 8), dim3(1024), 0, stream>>>(xT2, ih_rp, ih_pack,
                                                                   hh_bias, pre);

    void* kargs[] = {
        (void*)&hh_rp, (void*)&hh_pack,
        (void*)&pre,
        (void*)&hg,
        (void*)&regcnt, (void*)&barcnt, (void*)&bargen,
        (void*)&owncnt, (void*)&owngrp,
        (void*)&out,
    };
    hipLaunchCooperativeKernel((const void*)rnn_steps, dim3(RNN_BLOCKS), dim3(RNN_THREADS),
                               kargs, 0, stream);
}

// Round 10
// 1533.057 us; speedup vs baseline: 1.8458x; 1.0505x over previous
//
#include <hip/hip_runtime.h>
#include <hip/hip_cooperative_groups.h>
#include <math.h>

namespace cg = cooperative_groups;

#define B_ 64
#define T_ 128
#define I_ 1024
#define H_ 4096
#define XCDS 8

#define RNN_BLOCKS 256
#define RNN_THREADS 1024

#define MAXIT_IH 8    // 64 nnz/row registerized (Poisson(32)); tail fallback beyond

// ---------------- helpers ----------------
__device__ __forceinline__ unsigned short f2bf(float f) {
    unsigned int u = __float_as_uint(f);
    unsigned int r = (u + 0x7fffu + ((u >> 16) & 1u)) >> 16;
    return (unsigned short)r;
}

__device__ __forceinline__ void load4x16_sc0(const float* p0, const float* p1,
                                             const float* p2, const float* p3,
                                             float4& a, float4& b, float4& c, float4& d) {
    asm volatile(
        "global_load_dwordx4 %0, %4, off sc0\n\t"
        "global_load_dwordx4 %1, %5, off sc0\n\t"
        "global_load_dwordx4 %2, %6, off sc0\n\t"
        "global_load_dwordx4 %3, %7, off sc0\n\t"
        "s_waitcnt vmcnt(0)"
        : "=&v"(a), "=&v"(b), "=&v"(c), "=&v"(d)
        : "v"(p0), "v"(p1), "v"(p2), "v"(p3));
}

// ---------------- transpose x (B,T,I) -> xT2 (T, 8, I, 8) ----------------
__global__ void transpose_x(const float* __restrict__ x, float* __restrict__ xT2) {
    __shared__ float lds[8][129];
    int t  = blockIdx.z;
    int bg = blockIdx.y;
    int i0 = blockIdx.x * 128;
    int tx = threadIdx.x;   // 0..127
    int ty = threadIdx.y;   // 0..7
    int b = bg * 8 + ty;
    lds[ty][tx] = x[(size_t)b * T_ * I_ + (size_t)t * I_ + i0 + tx];
    __syncthreads();
    int n  = ty * 128 + tx;
    int ii = n >> 3;
    int bs = n & 7;
    xT2[(((size_t)t * 8 + bg) * I_ + i0 + ii) * 8 + bs] = lds[bs][ii];
}

// ---------------- CSR build ----------------
__global__ void hist_rows(const int* __restrict__ rows, int nnz, int* __restrict__ counts) {
    int k = blockIdx.x * blockDim.x + threadIdx.x;
    if (k < nnz) atomicAdd(&counts[rows[k]], 1);
}

__global__ void scan_rows(const int* __restrict__ counts, int* __restrict__ rp, int n) {
    int lane = threadIdx.x;      // 0..63
    int chunk = n / 64;
    int base = lane * chunk;
    int s = 0;
    for (int j = 0; j < chunk; ++j) s += counts[base + j];
    int pre = s;
    for (int off = 1; off < 64; off <<= 1) {
        int up = __shfl_up(pre, off, 64);
        if (lane >= off) pre += up;
    }
    int run = pre - s;
    for (int j = 0; j < chunk; ++j) { rp[base + j] = run; run += counts[base + j]; }
    if (lane == 63) rp[n] = run;
}

__global__ void scatter_pack(const int* __restrict__ rows, const int* __restrict__ cols,
                             const float* __restrict__ vals, int nnz,
                             const int* __restrict__ rp, int* __restrict__ cursor,
                             int2* __restrict__ pack) {
    int k = blockIdx.x * blockDim.x + threadIdx.x;
    if (k < nnz) {
        int r = rows[k];
        int pos = atomicAdd(&cursor[r], 1);
        pack[rp[r] + pos] = make_int2(cols[k], __float_as_int(vals[k]));
    }
}

// ---------------- kernel P: pre[t] = W_ih * x_t + bias  (bf16 out) ----------------
// r9 geometry (1024 thr, 16 waves share staging, 1 block/CU) + DOUBLE-BUFFERED
// staging: issue t+1's 32 KB into registers BEFORE computing t from the other
// LDS buffer; write after compute; ONE barrier per step (was two). Latency of
// the x_t load hides under the window compute. Window math bit-identical.
__global__ __launch_bounds__(1024)
void precompute_ih(const float* __restrict__ xT2,
                   const int* __restrict__ rp, const int2* __restrict__ pack,
                   const float* __restrict__ bias,
                   unsigned short* __restrict__ pre) {
    __shared__ __align__(16) float xs[2][I_ * 8];   // 64 KB double buffer
    int grp  = blockIdx.y;
    int wave = threadIdx.x >> 6;                  // 0..15
    int lane = threadIdx.x & 63;
    int rs = lane >> 3;   // row within group
    int u  = lane & 7;    // position within window

    int g = blockIdx.x * 16 + wave;               // 0..511
    int r = g * 8 + rs;
    int hb = rp[r];
    int len = rp[r + 1] - hb;
    int lm = len;
    lm = max(lm, __shfl_xor(lm, 8));
    lm = max(lm, __shfl_xor(lm, 16));
    lm = max(lm, __shfl_xor(lm, 32));
    int lmax = __builtin_amdgcn_readfirstlane(lm);
    float bsv = bias[r];

    // registerize the CSR slice (t-invariant): byte offsets pre-shifted
    int   pcol[MAXIT_IH];
    float pval[MAXIT_IH];
    #pragma unroll
    for (int it = 0; it < MAXIT_IH; ++it) {
        int2 pk = make_int2(0, 0);
        if (it * 8 + u < len) pk = pack[hb + it * 8 + u];
        pcol[it] = pk.x << 5;                 // col * 8 floats * 4 B
        pval[it] = __int_as_float(pk.y);
    }

    // prologue: stage t=0 into buffer 0
    {
        const float4* s = (const float4*)(xT2 + ((size_t)0 * 8 + grp) * (I_ * 8));
        float4* d = (float4*)xs[0];
        d[threadIdx.x]        = s[threadIdx.x];
        d[1024 + threadIdx.x] = s[1024 + threadIdx.x];
    }
    __syncthreads();

    for (int t = 0; t < T_; ++t) {
        int cur = t & 1;

        // issue next step's staging loads early (latency hides under compute)
        float4 st0, st1;
        bool havenext = (t + 1 < T_);
        if (havenext) {
            const float4* s = (const float4*)(xT2 + ((size_t)(t + 1) * 8 + grp) * (I_ * 8));
            st0 = s[threadIdx.x];
            st1 = s[1024 + threadIdx.x];
        }

        const char* xb = (const char*)xs[cur];
        float a[8];
        #pragma unroll
        for (int j = 0; j < 8; ++j) a[j] = 0.0f;

        // branchless registerized windows (padded lanes read xs[0], add +0.0)
        #pragma unroll
        for (int it = 0; it < MAXIT_IH; ++it) {
            const float* gp = (const float*)(xb + pcol[it]);
            float4 x0 = *(const float4*)gp;
            float4 x1 = *(const float4*)(gp + 4);
            float v = pval[it];
            a[0] += v * x0.x; a[1] += v * x0.y; a[2] += v * x0.z; a[3] += v * x0.w;
            a[4] += v * x1.x; a[5] += v * x1.y; a[6] += v * x1.z; a[7] += v * x1.w;
        }
        if (lmax > 8 * MAXIT_IH) {   // rare tail, same summation order
            int kk = hb + 8 * MAXIT_IH + u;
            for (int i = 8 * MAXIT_IH; i < lmax; i += 8, kk += 8) {
                int2 pk = make_int2(0, 0);
                if (i + u < len) pk = pack[kk];
                const float* gp = (const float*)(xb + ((size_t)pk.x << 5));
                float4 x0 = *(const float4*)gp;
                float4 x1 = *(const float4*)(gp + 4);
                float v = __int_as_float(pk.y);
                a[0] += v * x0.x; a[1] += v * x0.y; a[2] += v * x0.z; a[3] += v * x0.w;
                a[4] += v * x1.x; a[5] += v * x1.y; a[6] += v * x1.z; a[7] += v * x1.w;
            }
        }
        #pragma unroll
        for (int off = 1; off <= 4; off <<= 1) {
            #pragma unroll
            for (int j = 0; j < 8; ++j) a[j] += __shfl_xor(a[j], off);
        }
        float sel = (u == 0) ? a[0] : (u == 1) ? a[1] : (u == 2) ? a[2] : (u == 3) ? a[3]
                  : (u == 4) ? a[4] : (u == 5) ? a[5] : (u == 6) ? a[6] : a[7];
        float p = sel + bsv;
        int hf = u >> 2, cc = u & 3;
        pre[((size_t)(grp * 2 + hf) * T_ + t) * (H_ * 4) + (size_t)r * 4 + cc] = f2bf(p);

        // write-late: commit next step's staging to the other buffer
        if (havenext) {
            float4* d = (float4*)xs[cur ^ 1];
            d[threadIdx.x]        = st0;
            d[1024 + threadIdx.x] = st1;
        }
        __syncthreads();   // xs[cur^1] published; readers of xs[cur] done
    }
}

// ---------------- kernel R: persistent XCD-local recurrence ----------------
// EXACT round-8 version (proven 985 us): round-0 structure + 1-deep hhpack
// prefetch + early pre load. hg layout: hg[((grp*2 + parity)*2 + half) * (H_*4)]
__global__ __launch_bounds__(RNN_THREADS, 1)
void rnn_steps(const int* __restrict__ hhp, const int2* __restrict__ hhpack,
               const unsigned short* __restrict__ pre,
               float* __restrict__ hg,
               int* __restrict__ regcnt, int* __restrict__ barcnt, int* __restrict__ bargen,
               int* __restrict__ owncnt, int* __restrict__ owngrp,
               float* __restrict__ out) {
    cg::grid_group grid = cg::this_grid();
    __shared__ __align__(16) float sh[H_ * 4];   // 64 KB: h_prev, 4 batch cols of this half

    int tid = threadIdx.x;
    if (tid == 0) {
        int x;
        asm volatile("s_getreg_b32 %0, hwreg(HW_REG_XCC_ID)" : "=s"(x));
        x &= 7;
        int slot = __hip_atomic_fetch_add(&regcnt[x], 1, __ATOMIC_RELAXED,
                                          __HIP_MEMORY_SCOPE_AGENT);
        sh[0] = __int_as_float(x);
        sh[1] = __int_as_float(slot);
    }
    __syncthreads();
    int xcd  = __float_as_int(sh[0]);
    int slot = __float_as_int(sh[1]);
    grid.sync();

    if (blockIdx.x == 0 && tid == 0) {
        int list[XCDS]; int nz = 0;
        for (int j = 0; j < XCDS; ++j) {
            owncnt[j] = 0;
            if (__hip_atomic_load(&regcnt[j], __ATOMIC_RELAXED,
                                  __HIP_MEMORY_SCOPE_AGENT) > 0) list[nz++] = j;
        }
        int rr = 0;
        for (int j = 0; j < XCDS; ++j) {
            int present = __hip_atomic_load(&regcnt[j], __ATOMIC_RELAXED,
                                            __HIP_MEMORY_SCOPE_AGENT) > 0;
            int owner = present ? j : list[rr++ % nz];
            owngrp[owner * 8 + owncnt[owner]] = j;
            owncnt[owner] += 1;
        }
    }
    grid.sync();

    int nblk = __hip_atomic_load(&regcnt[xcd], __ATOMIC_RELAXED, __HIP_MEMORY_SCOPE_AGENT);
    int nown = owncnt[xcd];

    int wave = tid >> 6;
    int lane = tid & 63;
    int rs   = lane >> 3;
    int u    = lane & 7;

    // half assignment (robust to nblk==1)
    int hfbeg, hfend, mywave, nwh;
    if (nblk >= 2) {
        int hf = slot & 1;
        hfbeg = hf; hfend = hf + 1;
        int nhb = (hf == 0) ? ((nblk + 1) >> 1) : (nblk >> 1);
        mywave = (slot >> 1) * (RNN_THREADS / 64) + wave;
        nwh = nhb * (RNN_THREADS / 64);
    } else {
        hfbeg = 0; hfend = 2;
        mywave = wave; nwh = RNN_THREADS / 64;
    }

    int* bc = &barcnt[xcd * 32];
    int* bgen = &bargen[xcd * 32];

    for (int t = 0; t < T_; ++t) {
        for (int oi = 0; oi < nown; ++oi) {
            int grp = owngrp[xcd * 8 + oi];
            for (int hf = hfbeg; hf < hfend; ++hf) {
                const float* src = hg + (size_t)((grp * 2 + (t & 1)) * 2 + hf) * (H_ * 4);
                float*       dst = hg + (size_t)((grp * 2 + ((t + 1) & 1)) * 2 + hf) * (H_ * 4);

                // ---- fill sh with h_prev (sc0: bypass stale L1, hit local L2) ----
                __syncthreads();   // prior readers of sh are done
                {
                    float4 v0, v1, v2, v3;
                    const float* p0 = src + (size_t)(0 * 1024 + tid) * 4;
                    const float* p1 = src + (size_t)(1 * 1024 + tid) * 4;
                    const float* p2 = src + (size_t)(2 * 1024 + tid) * 4;
                    const float* p3 = src + (size_t)(3 * 1024 + tid) * 4;
                    load4x16_sc0(p0, p1, p2, p3, v0, v1, v2, v3);
                    float4* s4 = (float4*)sh;
                    s4[0 * 1024 + tid] = v0;
                    s4[1 * 1024 + tid] = v1;
                    s4[2 * 1024 + tid] = v2;
                    s4[3 * 1024 + tid] = v3;
                }
                __syncthreads();   // sh ready

                // ---- compute: hh SpMM rows + pre + tanh ----
                for (int g = mywave; g < H_ / 8; g += nwh) {
                    int r  = g * 8 + rs;
                    int hb = hhp[r], he = hhp[r + 1];
                    int len = he - hb;
                    int lmax = len;
                    lmax = max(lmax, __shfl_xor(lmax, 8));
                    lmax = max(lmax, __shfl_xor(lmax, 16));
                    lmax = max(lmax, __shfl_xor(lmax, 32));

                    // early pre load (u<8 index safe; consumed after reduce)
                    unsigned short pus =
                        pre[((size_t)(grp * 2 + hf) * T_ + t) * (H_ * 4) +
                            (size_t)r * 4 + u];

                    float a0 = 0.f, a1 = 0.f, a2 = 0.f, a3 = 0.f;
                    int kk = hb + u;
                    int2 pk = make_int2(0, 0);
                    if (u < len) pk = hhpack[kk];
                    for (int i = 0; i < lmax; i += 8) {
                        kk += 8;
                        int2 pkn = make_int2(0, 0);
                        if (i + 8 + u < len) pkn = hhpack[kk];   // next-window prefetch
                        float4 hv = ((const float4*)sh)[pk.x];
                        float v = __int_as_float(pk.y);
                        a0 += v * hv.x; a1 += v * hv.y; a2 += v * hv.z; a3 += v * hv.w;
                        pk = pkn;
                    }
                    #pragma unroll
                    for (int off = 1; off <= 4; off <<= 1) {
                        a0 += __shfl_xor(a0, off);
                        a1 += __shfl_xor(a1, off);
                        a2 += __shfl_xor(a2, off);
                        a3 += __shfl_xor(a3, off);
                    }
                    if (u < 4) {
                        float acc = (u == 0) ? a0 : (u == 1) ? a1 : (u == 2) ? a2 : a3;
                        float pv = __uint_as_float((unsigned int)pus << 16);
                        float h = tanhf(acc + pv);
                        dst[(size_t)r * 4 + u] = h;
                        int b = grp * 8 + hf * 4 + u;
                        out[(size_t)b * T_ * H_ + (size_t)t * H_ + r] = h;
                    }
                }
            }
        }

        // ---- per-XCD barrier (no cache maintenance) ----
        __syncthreads();   // drains this block's h stores to L2 (vmcnt(0) before s_barrier)
        if (tid == 0) {
            asm volatile("s_waitcnt vmcnt(0)" ::: "memory");
            int target = t + 1;
            int old = __hip_atomic_fetch_add(bc, 1, __ATOMIC_RELAXED,
                                             __HIP_MEMORY_SCOPE_AGENT);
            if (old == nblk - 1) {
                __hip_atomic_store(bc, 0, __ATOMIC_RELAXED, __HIP_MEMORY_SCOPE_AGENT);
                __hip_atomic_store(bgen, target, __ATOMIC_RELAXED, __HIP_MEMORY_SCOPE_AGENT);
            } else {
                while (__hip_atomic_load(bgen, __ATOMIC_RELAXED,
                                         __HIP_MEMORY_SCOPE_AGENT) < target) {
                    __builtin_amdgcn_s_sleep(1);
                }
            }
        }
        __syncthreads();
    }
}

// ---------------- host launch ----------------
extern "C" void kernel_launch(void* const* d_in, const int* in_sizes, int n_in,
                              void* d_out, int out_size, void* d_ws, size_t ws_size,
                              hipStream_t stream) {
    const float* x       = (const float*)d_in[0];
    const float* ih_vals = (const float*)d_in[1];
    const float* hh_vals = (const float*)d_in[2];
    const float* hh_bias = (const float*)d_in[3];
    const int*   ih_rows = (const int*)d_in[4];
    const int*   ih_cols = (const int*)d_in[5];
    const int*   hh_rows = (const int*)d_in[6];
    const int*   hh_cols = (const int*)d_in[7];
    float* out = (float*)d_out;

    const int nnz_ih = in_sizes[1];
    const int nnz_hh = in_sizes[2];

    char* ws = (char*)d_ws;
    size_t off = 0;
    auto alloc = [&](size_t bytes) -> void* {
        off = (off + 255) & ~(size_t)255;
        void* p = ws + off;
        off += bytes;
        return p;
    };

    float* xT2   = (float*)alloc((size_t)T_ * 8 * I_ * 8 * sizeof(float));
    int*   ih_rp = (int*)  alloc((H_ + 1) * sizeof(int));
    int*   hh_rp = (int*)  alloc((H_ + 1) * sizeof(int));

    const int ZINTS = 4 * H_ + 64 + 8 * 32 + 8 * 32 + 8 + 64;
    int* zbase  = (int*)alloc((size_t)ZINTS * sizeof(int));
    int* ih_cnt = zbase;
    int* ih_cur = zbase + H_;
    int* hh_cnt = zbase + 2 * H_;
    int* hh_cur = zbase + 3 * H_;
    int* regcnt = zbase + 4 * H_;
    int* barcnt = regcnt + 64;
    int* bargen = barcnt + 8 * 32;
    int* owncnt = bargen + 8 * 32;
    int* owngrp = owncnt + 8;

    int2* ih_pack = (int2*)alloc((size_t)nnz_ih * sizeof(int2));
    int2* hh_pack = (int2*)alloc((size_t)nnz_hh * sizeof(int2));
    float* hg     = (float*)alloc((size_t)XCDS * 2 * 2 * H_ * 4 * sizeof(float));  // 2 MB
    unsigned short* pre = (unsigned short*)alloc((size_t)16 * T_ * H_ * 4 * sizeof(unsigned short)); // 67 MB

    hipMemsetAsync(zbase, 0, (size_t)ZINTS * sizeof(int), stream);
    hipMemsetAsync(hg, 0, (size_t)XCDS * 2 * 2 * H_ * 4 * sizeof(float), stream);

    transpose_x<<<dim3(I_ / 128, 8, T_), dim3(128, 8), 0, stream>>>(x, xT2);

    hist_rows<<<(nnz_ih + 255) / 256, 256, 0, stream>>>(ih_rows, nnz_ih, ih_cnt);
    scan_rows<<<1, 64, 0, stream>>>(ih_cnt, ih_rp, H_);
    scatter_pack<<<(nnz_ih + 255) / 256, 256, 0, stream>>>(ih_rows, ih_cols, ih_vals, nnz_ih,
                                                           ih_rp, ih_cur, ih_pack);
    hist_rows<<<(nnz_hh + 255) / 256, 256, 0, stream>>>(hh_rows, nnz_hh, hh_cnt);
    scan_rows<<<1, 64, 0, stream>>>(hh_cnt, hh_rp, H_);
    scatter_pack<<<(nnz_hh + 255) / 256, 256, 0, stream>>>(hh_rows, hh_cols, hh_vals, nnz_hh,
                                                           hh_rp, hh_cur, hh_pack);

    precompute_ih<<<dim3(H_ / 8 / 16, 8), dim3(1024), 0, stream>>>(xT2, ih_rp, ih_pack,
                                                                   hh_bias, pre);

    void* kargs[] = {
        (void*)&hh_rp, (void*)&hh_pack,
        (void*)&pre,
        (void*)&hg,
        (void*)&regcnt, (void*)&barcnt, (void*)&bargen,
        (void*)&owncnt, (void*)&owngrp,
        (void*)&out,
    };
    hipLaunchCooperativeKernel((const void*)rnn_steps, dim3(RNN_BLOCKS), dim3(RNN_THREADS),
                               kargs, 0, stream);
}

// Round 11
// 1516.260 us; speedup vs baseline: 1.8662x; 1.0111x over previous
//
#include <hip/hip_runtime.h>
#include <hip/hip_cooperative_groups.h>
#include <math.h>

namespace cg = cooperative_groups;

#define B_ 64
#define T_ 128
#define I_ 1024
#define H_ 4096
#define XCDS 8

#define RNN_BLOCKS 256
#define RNN_THREADS 1024

#define MAXIT_IH 8    // 64 nnz/row registerized (Poisson(32)); tail fallback beyond

// ---------------- helpers ----------------
__device__ __forceinline__ unsigned short f2bf(float f) {
    unsigned int u = __float_as_uint(f);
    unsigned int r = (u + 0x7fffu + ((u >> 16) & 1u)) >> 16;
    return (unsigned short)r;
}

__device__ __forceinline__ void load2x16_sc0(const void* p0, const void* p1,
                                             uint4& a, uint4& b) {
    asm volatile(
        "global_load_dwordx4 %0, %2, off sc0\n\t"
        "global_load_dwordx4 %1, %3, off sc0\n\t"
        "s_waitcnt vmcnt(0)"
        : "=&v"(a), "=&v"(b)
        : "v"(p0), "v"(p1));
}

// ---------------- transpose x (B,T,I) -> xT2 (T, 8, I, 8) ----------------
__global__ void transpose_x(const float* __restrict__ x, float* __restrict__ xT2) {
    __shared__ float lds[8][129];
    int t  = blockIdx.z;
    int bg = blockIdx.y;
    int i0 = blockIdx.x * 128;
    int tx = threadIdx.x;   // 0..127
    int ty = threadIdx.y;   // 0..7
    int b = bg * 8 + ty;
    lds[ty][tx] = x[(size_t)b * T_ * I_ + (size_t)t * I_ + i0 + tx];
    __syncthreads();
    int n  = ty * 128 + tx;
    int ii = n >> 3;
    int bs = n & 7;
    xT2[(((size_t)t * 8 + bg) * I_ + i0 + ii) * 8 + bs] = lds[bs][ii];
}

// ---------------- CSR build ----------------
__global__ void hist_rows(const int* __restrict__ rows, int nnz, int* __restrict__ counts) {
    int k = blockIdx.x * blockDim.x + threadIdx.x;
    if (k < nnz) atomicAdd(&counts[rows[k]], 1);
}

__global__ void scan_rows(const int* __restrict__ counts, int* __restrict__ rp, int n) {
    int lane = threadIdx.x;      // 0..63
    int chunk = n / 64;
    int base = lane * chunk;
    int s = 0;
    for (int j = 0; j < chunk; ++j) s += counts[base + j];
    int pre = s;
    for (int off = 1; off < 64; off <<= 1) {
        int up = __shfl_up(pre, off, 64);
        if (lane >= off) pre += up;
    }
    int run = pre - s;
    for (int j = 0; j < chunk; ++j) { rp[base + j] = run; run += counts[base + j]; }
    if (lane == 63) rp[n] = run;
}

__global__ void scatter_pack(const int* __restrict__ rows, const int* __restrict__ cols,
                             const float* __restrict__ vals, int nnz,
                             const int* __restrict__ rp, int* __restrict__ cursor,
                             int2* __restrict__ pack) {
    int k = blockIdx.x * blockDim.x + threadIdx.x;
    if (k < nnz) {
        int r = rows[k];
        int pos = atomicAdd(&cursor[r], 1);
        pack[rp[r] + pos] = make_int2(cols[k], __float_as_int(vals[k]));
    }
}

// ---------------- kernel P: pre[t] = W_ih * x_t + bias  (bf16 out) ----------------
// r10 proven form: 1024 thr, 16 waves share double-buffered x_t staging,
// issue-early/write-late, one barrier per step. CSR slice registerized.
__global__ __launch_bounds__(1024)
void precompute_ih(const float* __restrict__ xT2,
                   const int* __restrict__ rp, const int2* __restrict__ pack,
                   const float* __restrict__ bias,
                   unsigned short* __restrict__ pre) {
    __shared__ __align__(16) float xs[2][I_ * 8];   // 64 KB double buffer
    int grp  = blockIdx.y;
    int wave = threadIdx.x >> 6;                  // 0..15
    int lane = threadIdx.x & 63;
    int rs = lane >> 3;   // row within group
    int u  = lane & 7;    // position within window

    int g = blockIdx.x * 16 + wave;               // 0..511
    int r = g * 8 + rs;
    int hb = rp[r];
    int len = rp[r + 1] - hb;
    int lm = len;
    lm = max(lm, __shfl_xor(lm, 8));
    lm = max(lm, __shfl_xor(lm, 16));
    lm = max(lm, __shfl_xor(lm, 32));
    int lmax = __builtin_amdgcn_readfirstlane(lm);
    float bsv = bias[r];

    // registerize the CSR slice (t-invariant): byte offsets pre-shifted
    int   pcol[MAXIT_IH];
    float pval[MAXIT_IH];
    #pragma unroll
    for (int it = 0; it < MAXIT_IH; ++it) {
        int2 pk = make_int2(0, 0);
        if (it * 8 + u < len) pk = pack[hb + it * 8 + u];
        pcol[it] = pk.x << 5;                 // col * 8 floats * 4 B
        pval[it] = __int_as_float(pk.y);
    }

    // prologue: stage t=0 into buffer 0
    {
        const float4* s = (const float4*)(xT2 + ((size_t)0 * 8 + grp) * (I_ * 8));
        float4* d = (float4*)xs[0];
        d[threadIdx.x]        = s[threadIdx.x];
        d[1024 + threadIdx.x] = s[1024 + threadIdx.x];
    }
    __syncthreads();

    for (int t = 0; t < T_; ++t) {
        int cur = t & 1;

        // issue next step's staging loads early (latency hides under compute)
        float4 st0, st1;
        bool havenext = (t + 1 < T_);
        if (havenext) {
            const float4* s = (const float4*)(xT2 + ((size_t)(t + 1) * 8 + grp) * (I_ * 8));
            st0 = s[threadIdx.x];
            st1 = s[1024 + threadIdx.x];
        }

        const char* xb = (const char*)xs[cur];
        float a[8];
        #pragma unroll
        for (int j = 0; j < 8; ++j) a[j] = 0.0f;

        // branchless registerized windows (padded lanes read xs[0], add +0.0)
        #pragma unroll
        for (int it = 0; it < MAXIT_IH; ++it) {
            const float* gp = (const float*)(xb + pcol[it]);
            float4 x0 = *(const float4*)gp;
            float4 x1 = *(const float4*)(gp + 4);
            float v = pval[it];
            a[0] += v * x0.x; a[1] += v * x0.y; a[2] += v * x0.z; a[3] += v * x0.w;
            a[4] += v * x1.x; a[5] += v * x1.y; a[6] += v * x1.z; a[7] += v * x1.w;
        }
        if (lmax > 8 * MAXIT_IH) {   // rare tail, same summation order
            int kk = hb + 8 * MAXIT_IH + u;
            for (int i = 8 * MAXIT_IH; i < lmax; i += 8, kk += 8) {
                int2 pk = make_int2(0, 0);
                if (i + u < len) pk = pack[kk];
                const float* gp = (const float*)(xb + ((size_t)pk.x << 5));
                float4 x0 = *(const float4*)gp;
                float4 x1 = *(const float4*)(gp + 4);
                float v = __int_as_float(pk.y);
                a[0] += v * x0.x; a[1] += v * x0.y; a[2] += v * x0.z; a[3] += v * x0.w;
                a[4] += v * x1.x; a[5] += v * x1.y; a[6] += v * x1.z; a[7] += v * x1.w;
            }
        }
        #pragma unroll
        for (int off = 1; off <= 4; off <<= 1) {
            #pragma unroll
            for (int j = 0; j < 8; ++j) a[j] += __shfl_xor(a[j], off);
        }
        float sel = (u == 0) ? a[0] : (u == 1) ? a[1] : (u == 2) ? a[2] : (u == 3) ? a[3]
                  : (u == 4) ? a[4] : (u == 5) ? a[5] : (u == 6) ? a[6] : a[7];
        float p = sel + bsv;
        int hf = u >> 2, cc = u & 3;
        pre[((size_t)(grp * 2 + hf) * T_ + t) * (H_ * 4) + (size_t)r * 4 + cc] = f2bf(p);

        // write-late: commit next step's staging to the other buffer
        if (havenext) {
            float4* d = (float4*)xs[cur ^ 1];
            d[threadIdx.x]        = st0;
            d[1024 + threadIdx.x] = st1;
        }
        __syncthreads();   // xs[cur^1] published; readers of xs[cur] done
    }
}

// ---------------- kernel R: persistent XCD-local recurrence ----------------
// r8 proven structure (1-deep hhpack prefetch + early pre load), state in BF16:
// hg/sh hold bf16 h (sh 32 KB, gather ds_read_b64, refill 32 KB). Same loads,
// same order, same FMA order; 4 unpack ops per window added.
// hg layout: hg[((grp*2 + parity)*2 + half) * (H_*4)]  (ushort elements)
__global__ __launch_bounds__(RNN_THREADS, 1)
void rnn_steps(const int* __restrict__ hhp, const int2* __restrict__ hhpack,
               const unsigned short* __restrict__ pre,
               unsigned short* __restrict__ hg,
               int* __restrict__ regcnt, int* __restrict__ barcnt, int* __restrict__ bargen,
               int* __restrict__ owncnt, int* __restrict__ owngrp,
               float* __restrict__ out) {
    cg::grid_group grid = cg::this_grid();
    __shared__ __align__(16) unsigned short sh[H_ * 4];   // 32 KB: bf16 h_prev
    __shared__ int meta[2];

    int tid = threadIdx.x;
    if (tid == 0) {
        int x;
        asm volatile("s_getreg_b32 %0, hwreg(HW_REG_XCC_ID)" : "=s"(x));
        x &= 7;
        int slot = __hip_atomic_fetch_add(&regcnt[x], 1, __ATOMIC_RELAXED,
                                          __HIP_MEMORY_SCOPE_AGENT);
        meta[0] = x;
        meta[1] = slot;
    }
    __syncthreads();
    int xcd  = meta[0];
    int slot = meta[1];
    grid.sync();

    if (blockIdx.x == 0 && tid == 0) {
        int list[XCDS]; int nz = 0;
        for (int j = 0; j < XCDS; ++j) {
            owncnt[j] = 0;
            if (__hip_atomic_load(&regcnt[j], __ATOMIC_RELAXED,
                                  __HIP_MEMORY_SCOPE_AGENT) > 0) list[nz++] = j;
        }
        int rr = 0;
        for (int j = 0; j < XCDS; ++j) {
            int present = __hip_atomic_load(&regcnt[j], __ATOMIC_RELAXED,
                                            __HIP_MEMORY_SCOPE_AGENT) > 0;
            int owner = present ? j : list[rr++ % nz];
            owngrp[owner * 8 + owncnt[owner]] = j;
            owncnt[owner] += 1;
        }
    }
    grid.sync();

    int nblk = __hip_atomic_load(&regcnt[xcd], __ATOMIC_RELAXED, __HIP_MEMORY_SCOPE_AGENT);
    int nown = owncnt[xcd];

    int wave = tid >> 6;
    int lane = tid & 63;
    int rs   = lane >> 3;
    int u    = lane & 7;

    // half assignment (robust to nblk==1)
    int hfbeg, hfend, mywave, nwh;
    if (nblk >= 2) {
        int hf = slot & 1;
        hfbeg = hf; hfend = hf + 1;
        int nhb = (hf == 0) ? ((nblk + 1) >> 1) : (nblk >> 1);
        mywave = (slot >> 1) * (RNN_THREADS / 64) + wave;
        nwh = nhb * (RNN_THREADS / 64);
    } else {
        hfbeg = 0; hfend = 2;
        mywave = wave; nwh = RNN_THREADS / 64;
    }

    int* bc = &barcnt[xcd * 32];
    int* bgen = &bargen[xcd * 32];

    for (int t = 0; t < T_; ++t) {
        for (int oi = 0; oi < nown; ++oi) {
            int grp = owngrp[xcd * 8 + oi];
            for (int hf = hfbeg; hf < hfend; ++hf) {
                const unsigned short* src =
                    hg + (size_t)((grp * 2 + (t & 1)) * 2 + hf) * (H_ * 4);
                unsigned short* dst =
                    hg + (size_t)((grp * 2 + ((t + 1) & 1)) * 2 + hf) * (H_ * 4);

                // ---- fill sh with bf16 h_prev (sc0: bypass stale L1, hit L2) ----
                __syncthreads();   // prior readers of sh are done
                {
                    uint4 v0, v1;
                    const char* s = (const char*)src;
                    load2x16_sc0(s + (size_t)tid * 16,
                                 s + (size_t)(1024 + tid) * 16, v0, v1);
                    uint4* s4 = (uint4*)sh;
                    s4[tid]        = v0;
                    s4[1024 + tid] = v1;
                }
                __syncthreads();   // sh ready

                // ---- compute: hh SpMM rows + pre + tanh ----
                for (int g = mywave; g < H_ / 8; g += nwh) {
                    int r  = g * 8 + rs;
                    int hb = hhp[r], he = hhp[r + 1];
                    int len = he - hb;
                    int lmax = len;
                    lmax = max(lmax, __shfl_xor(lmax, 8));
                    lmax = max(lmax, __shfl_xor(lmax, 16));
                    lmax = max(lmax, __shfl_xor(lmax, 32));

                    // early pre load (u<8 index safe; consumed after reduce)
                    unsigned short pus =
                        pre[((size_t)(grp * 2 + hf) * T_ + t) * (H_ * 4) +
                            (size_t)r * 4 + u];

                    float a0 = 0.f, a1 = 0.f, a2 = 0.f, a3 = 0.f;
                    int kk = hb + u;
                    int2 pk = make_int2(0, 0);
                    if (u < len) pk = hhpack[kk];
                    for (int i = 0; i < lmax; i += 8) {
                        kk += 8;
                        int2 pkn = make_int2(0, 0);
                        if (i + 8 + u < len) pkn = hhpack[kk];   // next-window prefetch
                        uint2 hw = *(const uint2*)((const char*)sh + ((size_t)pk.x << 3));
                        float v = __int_as_float(pk.y);
                        a0 += v * __uint_as_float(hw.x << 16);
                        a1 += v * __uint_as_float(hw.x & 0xffff0000u);
                        a2 += v * __uint_as_float(hw.y << 16);
                        a3 += v * __uint_as_float(hw.y & 0xffff0000u);
                        pk = pkn;
                    }
                    #pragma unroll
                    for (int off = 1; off <= 4; off <<= 1) {
                        a0 += __shfl_xor(a0, off);
                        a1 += __shfl_xor(a1, off);
                        a2 += __shfl_xor(a2, off);
                        a3 += __shfl_xor(a3, off);
                    }
                    if (u < 4) {
                        float acc = (u == 0) ? a0 : (u == 1) ? a1 : (u == 2) ? a2 : a3;
                        float pv = __uint_as_float((unsigned int)pus << 16);
                        float h = tanhf(acc + pv);
                        dst[(size_t)r * 4 + u] = f2bf(h);
                        int b = grp * 8 + hf * 4 + u;
                        out[(size_t)b * T_ * H_ + (size_t)t * H_ + r] = h;
                    }
                }
            }
        }

        // ---- per-XCD barrier (no cache maintenance) ----
        __syncthreads();   // drains this block's h stores to L2 (vmcnt(0) before s_barrier)
        if (tid == 0) {
            asm volatile("s_waitcnt vmcnt(0)" ::: "memory");
            int target = t + 1;
            int old = __hip_atomic_fetch_add(bc, 1, __ATOMIC_RELAXED,
                                             __HIP_MEMORY_SCOPE_AGENT);
            if (old == nblk - 1) {
                __hip_atomic_store(bc, 0, __ATOMIC_RELAXED, __HIP_MEMORY_SCOPE_AGENT);
                __hip_atomic_store(bgen, target, __ATOMIC_RELAXED, __HIP_MEMORY_SCOPE_AGENT);
            } else {
                while (__hip_atomic_load(bgen, __ATOMIC_RELAXED,
                                         __HIP_MEMORY_SCOPE_AGENT) < target) {
                    __builtin_amdgcn_s_sleep(1);
                }
            }
        }
        __syncthreads();
    }
}

// ---------------- host launch ----------------
extern "C" void kernel_launch(void* const* d_in, const int* in_sizes, int n_in,
                              void* d_out, int out_size, void* d_ws, size_t ws_size,
                              hipStream_t stream) {
    const float* x       = (const float*)d_in[0];
    const float* ih_vals = (const float*)d_in[1];
    const float* hh_vals = (const float*)d_in[2];
    const float* hh_bias = (const float*)d_in[3];
    const int*   ih_rows = (const int*)d_in[4];
    const int*   ih_cols = (const int*)d_in[5];
    const int*   hh_rows = (const int*)d_in[6];
    const int*   hh_cols = (const int*)d_in[7];
    float* out = (float*)d_out;

    const int nnz_ih = in_sizes[1];
    const int nnz_hh = in_sizes[2];

    char* ws = (char*)d_ws;
    size_t off = 0;
    auto alloc = [&](size_t bytes) -> void* {
        off = (off + 255) & ~(size_t)255;
        void* p = ws + off;
        off += bytes;
        return p;
    };

    float* xT2   = (float*)alloc((size_t)T_ * 8 * I_ * 8 * sizeof(float));
    int*   ih_rp = (int*)  alloc((H_ + 1) * sizeof(int));
    int*   hh_rp = (int*)  alloc((H_ + 1) * sizeof(int));

    const int ZINTS = 4 * H_ + 64 + 8 * 32 + 8 * 32 + 8 + 64;
    int* zbase  = (int*)alloc((size_t)ZINTS * sizeof(int));
    int* ih_cnt = zbase;
    int* ih_cur = zbase + H_;
    int* hh_cnt = zbase + 2 * H_;
    int* hh_cur = zbase + 3 * H_;
    int* regcnt = zbase + 4 * H_;
    int* barcnt = regcnt + 64;
    int* bargen = barcnt + 8 * 32;
    int* owncnt = bargen + 8 * 32;
    int* owngrp = owncnt + 8;

    int2* ih_pack = (int2*)alloc((size_t)nnz_ih * sizeof(int2));
    int2* hh_pack = (int2*)alloc((size_t)nnz_hh * sizeof(int2));
    unsigned short* hg = (unsigned short*)alloc((size_t)XCDS * 2 * 2 * H_ * 4 * sizeof(unsigned short)); // 1 MB
    unsigned short* pre = (unsigned short*)alloc((size_t)16 * T_ * H_ * 4 * sizeof(unsigned short)); // 67 MB

    hipMemsetAsync(zbase, 0, (size_t)ZINTS * sizeof(int), stream);
    hipMemsetAsync(hg, 0, (size_t)XCDS * 2 * 2 * H_ * 4 * sizeof(unsigned short), stream);

    transpose_x<<<dim3(I_ / 128, 8, T_), dim3(128, 8), 0, stream>>>(x, xT2);

    hist_rows<<<(nnz_ih + 255) / 256, 256, 0, stream>>>(ih_rows, nnz_ih, ih_cnt);
    scan_rows<<<1, 64, 0, stream>>>(ih_cnt, ih_rp, H_);
    scatter_pack<<<(nnz_ih + 255) / 256, 256, 0, stream>>>(ih_rows, ih_cols, ih_vals, nnz_ih,
                                                           ih_rp, ih_cur, ih_pack);
    hist_rows<<<(nnz_hh + 255) / 256, 256, 0, stream>>>(hh_rows, nnz_hh, hh_cnt);
    scan_rows<<<1, 64, 0, stream>>>(hh_cnt, hh_rp, H_);
    scatter_pack<<<(nnz_hh + 255) / 256, 256, 0, stream>>>(hh_rows, hh_cols, hh_vals, nnz_hh,
                                                           hh_rp, hh_cur, hh_pack);

    precompute_ih<<<dim3(H_ / 8 / 16, 8), dim3(1024), 0, stream>>>(xT2, ih_rp, ih_pack,
                                                                   hh_bias, pre);

    void* kargs[] = {
        (void*)&hh_rp, (void*)&hh_pack,
        (void*)&pre,
        (void*)&hg,
        (void*)&regcnt, (void*)&barcnt, (void*)&bargen,
        (void*)&owncnt, (void*)&owngrp,
        (void*)&out,
    };
    hipLaunchCooperativeKernel((const void*)rnn_steps, dim3(RNN_BLOCKS), dim3(RNN_THREADS),
                               kargs, 0, stream);
}

// Round 12
// 1438.911 us; speedup vs baseline: 1.9665x; 1.0538x over previous
//
#include <hip/hip_runtime.h>
#include <hip/hip_cooperative_groups.h>
#include <math.h>

namespace cg = cooperative_groups;

#define B_ 64
#define T_ 128
#define I_ 1024
#define H_ 4096
#define XCDS 8

#define RNN_BLOCKS 256
#define RNN_THREADS 1024

#define MAXIT_IH 8    // 64 nnz/row registerized (Poisson(32)); tail fallback beyond

// ---------------- helpers ----------------
__device__ __forceinline__ unsigned short f2bf(float f) {
    unsigned int u = __float_as_uint(f);
    unsigned int r = (u + 0x7fffu + ((u >> 16) & 1u)) >> 16;
    return (unsigned short)r;
}

__device__ __forceinline__ void load2x16_sc0(const void* p0, const void* p1,
                                             uint4& a, uint4& b) {
    asm volatile(
        "global_load_dwordx4 %0, %2, off sc0\n\t"
        "global_load_dwordx4 %1, %3, off sc0\n\t"
        "s_waitcnt vmcnt(0)"
        : "=&v"(a), "=&v"(b)
        : "v"(p0), "v"(p1));
}

// ---------------- transpose x (B,T,I) -> xT2 (T, 8, I, 8) bf16 ----------------
__global__ void transpose_x(const float* __restrict__ x, unsigned short* __restrict__ xT2) {
    __shared__ float lds[8][129];
    int t  = blockIdx.z;
    int bg = blockIdx.y;
    int i0 = blockIdx.x * 128;
    int tx = threadIdx.x;   // 0..127
    int ty = threadIdx.y;   // 0..7
    int b = bg * 8 + ty;
    lds[ty][tx] = x[(size_t)b * T_ * I_ + (size_t)t * I_ + i0 + tx];
    __syncthreads();
    int n  = ty * 128 + tx;
    int ii = n >> 3;
    int bs = n & 7;
    xT2[(((size_t)t * 8 + bg) * I_ + i0 + ii) * 8 + bs] = f2bf(lds[bs][ii]);
}

// ---------------- CSR build ----------------
__global__ void hist_rows(const int* __restrict__ rows, int nnz, int* __restrict__ counts) {
    int k = blockIdx.x * blockDim.x + threadIdx.x;
    if (k < nnz) atomicAdd(&counts[rows[k]], 1);
}

// pad each group-of-8 rows to (group max rounded up to 8): uniform len, no guards
__global__ void pad_counts(const int* __restrict__ cnt, int* __restrict__ pcnt) {
    int grp = blockIdx.x * blockDim.x + threadIdx.x;
    if (grp >= H_ / 8) return;
    int m = 0;
    #pragma unroll
    for (int j = 0; j < 8; ++j) m = max(m, cnt[grp * 8 + j]);
    m = (m + 7) & ~7;
    #pragma unroll
    for (int j = 0; j < 8; ++j) pcnt[grp * 8 + j] = m;
}

__global__ void scan_rows(const int* __restrict__ counts, int* __restrict__ rp, int n) {
    int lane = threadIdx.x;      // 0..63
    int chunk = n / 64;
    int base = lane * chunk;
    int s = 0;
    for (int j = 0; j < chunk; ++j) s += counts[base + j];
    int pre = s;
    for (int off = 1; off < 64; off <<= 1) {
        int up = __shfl_up(pre, off, 64);
        if (lane >= off) pre += up;
    }
    int run = pre - s;
    for (int j = 0; j < chunk; ++j) { rp[base + j] = run; run += counts[base + j]; }
    if (lane == 63) rp[n] = run;
}

__global__ void scatter_pack(const int* __restrict__ rows, const int* __restrict__ cols,
                             const float* __restrict__ vals, int nnz,
                             const int* __restrict__ rp, int* __restrict__ cursor,
                             int2* __restrict__ pack) {
    int k = blockIdx.x * blockDim.x + threadIdx.x;
    if (k < nnz) {
        int r = rows[k];
        int pos = atomicAdd(&cursor[r], 1);
        pack[rp[r] + pos] = make_int2(cols[k], __float_as_int(vals[k]));
    }
}

// ---------------- kernel P: pre[t] = W_ih * x_t + bias  (bf16 out) ----------------
// r10 proven form (16 waves share double-buffered staging, issue-early/write-late,
// one barrier/step) with BF16 x: one b128 gather per window (was two), 16 KB staging.
__global__ __launch_bounds__(1024)
void precompute_ih(const unsigned short* __restrict__ xT2,
                   const int* __restrict__ rp, const int2* __restrict__ pack,
                   const float* __restrict__ bias,
                   unsigned short* __restrict__ pre) {
    __shared__ __align__(16) unsigned short xs[2][I_ * 8];   // 2 x 16 KB double buffer
    int grp  = blockIdx.y;
    int wave = threadIdx.x >> 6;                  // 0..15
    int lane = threadIdx.x & 63;
    int rs = lane >> 3;   // row within group
    int u  = lane & 7;    // position within window

    int g = blockIdx.x * 16 + wave;               // 0..511
    int r = g * 8 + rs;
    int hb = rp[r];
    int len = rp[r + 1] - hb;
    int lm = len;
    lm = max(lm, __shfl_xor(lm, 8));
    lm = max(lm, __shfl_xor(lm, 16));
    lm = max(lm, __shfl_xor(lm, 32));
    int lmax = __builtin_amdgcn_readfirstlane(lm);
    float bsv = bias[r];

    // registerize the CSR slice (t-invariant): byte offsets pre-shifted
    int   pcol[MAXIT_IH];
    float pval[MAXIT_IH];
    #pragma unroll
    for (int it = 0; it < MAXIT_IH; ++it) {
        int2 pk = make_int2(0, 0);
        if (it * 8 + u < len) pk = pack[hb + it * 8 + u];
        pcol[it] = pk.x << 4;                 // col * 8 bf16 * 2 B
        pval[it] = __int_as_float(pk.y);
    }

    // prologue: stage t=0 into buffer 0
    {
        const uint4* s = (const uint4*)(xT2 + ((size_t)0 * 8 + grp) * (I_ * 8));
        ((uint4*)xs[0])[threadIdx.x] = s[threadIdx.x];   // 1024 x 16 B = 16 KB
    }
    __syncthreads();

    for (int t = 0; t < T_; ++t) {
        int cur = t & 1;

        // issue next step's staging load early (latency hides under compute)
        uint4 st0;
        bool havenext = (t + 1 < T_);
        if (havenext) {
            const uint4* s = (const uint4*)(xT2 + ((size_t)(t + 1) * 8 + grp) * (I_ * 8));
            st0 = s[threadIdx.x];
        }

        const char* xb = (const char*)xs[cur];
        float a[8];
        #pragma unroll
        for (int j = 0; j < 8; ++j) a[j] = 0.0f;

        // branchless registerized windows (padded lanes read col 0, add +0.0)
        #pragma unroll
        for (int it = 0; it < MAXIT_IH; ++it) {
            uint4 xw = *(const uint4*)(xb + pcol[it]);
            float v = pval[it];
            a[0] += v * __uint_as_float(xw.x << 16);
            a[1] += v * __uint_as_float(xw.x & 0xffff0000u);
            a[2] += v * __uint_as_float(xw.y << 16);
            a[3] += v * __uint_as_float(xw.y & 0xffff0000u);
            a[4] += v * __uint_as_float(xw.z << 16);
            a[5] += v * __uint_as_float(xw.z & 0xffff0000u);
            a[6] += v * __uint_as_float(xw.w << 16);
            a[7] += v * __uint_as_float(xw.w & 0xffff0000u);
        }
        if (lmax > 8 * MAXIT_IH) {   // rare tail, same summation order
            int kk = hb + 8 * MAXIT_IH + u;
            for (int i = 8 * MAXIT_IH; i < lmax; i += 8, kk += 8) {
                int2 pk = make_int2(0, 0);
                if (i + u < len) pk = pack[kk];
                uint4 xw = *(const uint4*)(xb + ((size_t)pk.x << 4));
                float v = __int_as_float(pk.y);
                a[0] += v * __uint_as_float(xw.x << 16);
                a[1] += v * __uint_as_float(xw.x & 0xffff0000u);
                a[2] += v * __uint_as_float(xw.y << 16);
                a[3] += v * __uint_as_float(xw.y & 0xffff0000u);
                a[4] += v * __uint_as_float(xw.z << 16);
                a[5] += v * __uint_as_float(xw.z & 0xffff0000u);
                a[6] += v * __uint_as_float(xw.w << 16);
                a[7] += v * __uint_as_float(xw.w & 0xffff0000u);
            }
        }
        #pragma unroll
        for (int off = 1; off <= 4; off <<= 1) {
            #pragma unroll
            for (int j = 0; j < 8; ++j) a[j] += __shfl_xor(a[j], off);
        }
        float sel = (u == 0) ? a[0] : (u == 1) ? a[1] : (u == 2) ? a[2] : (u == 3) ? a[3]
                  : (u == 4) ? a[4] : (u == 5) ? a[5] : (u == 6) ? a[6] : a[7];
        float p = sel + bsv;
        int hf = u >> 2, cc = u & 3;
        pre[((size_t)(grp * 2 + hf) * T_ + t) * (H_ * 4) + (size_t)r * 4 + cc] = f2bf(p);

        // write-late: commit next step's staging to the other buffer
        if (havenext) {
            ((uint4*)xs[cur ^ 1])[threadIdx.x] = st0;
        }
        __syncthreads();   // xs[cur^1] published; readers of xs[cur] done
    }
}

// ---------------- kernel R: persistent XCD-local recurrence ----------------
// r11 structure (bf16 state, 1-deep hhpack prefetch, early pre load) with
// PADDED hh CSR: uniform group len -> no shuffle-max, unconditional loads
// (padded entries are (0,0), contributing +0.0 in identical order).
// hg layout: hg[((grp*2 + parity)*2 + half) * (H_*4)]  (ushort elements)
__global__ __launch_bounds__(RNN_THREADS, 1)
void rnn_steps(const int* __restrict__ hhp, const int2* __restrict__ hhpack,
               const unsigned short* __restrict__ pre,
               unsigned short* __restrict__ hg,
               int* __restrict__ regcnt, int* __restrict__ barcnt, int* __restrict__ bargen,
               int* __restrict__ owncnt, int* __restrict__ owngrp,
               float* __restrict__ out) {
    cg::grid_group grid = cg::this_grid();
    __shared__ __align__(16) unsigned short sh[H_ * 4];   // 32 KB: bf16 h_prev
    __shared__ int meta[2];

    int tid = threadIdx.x;
    if (tid == 0) {
        int x;
        asm volatile("s_getreg_b32 %0, hwreg(HW_REG_XCC_ID)" : "=s"(x));
        x &= 7;
        int slot = __hip_atomic_fetch_add(&regcnt[x], 1, __ATOMIC_RELAXED,
                                          __HIP_MEMORY_SCOPE_AGENT);
        meta[0] = x;
        meta[1] = slot;
    }
    __syncthreads();
    int xcd  = meta[0];
    int slot = meta[1];
    grid.sync();

    if (blockIdx.x == 0 && tid == 0) {
        int list[XCDS]; int nz = 0;
        for (int j = 0; j < XCDS; ++j) {
            owncnt[j] = 0;
            if (__hip_atomic_load(&regcnt[j], __ATOMIC_RELAXED,
                                  __HIP_MEMORY_SCOPE_AGENT) > 0) list[nz++] = j;
        }
        int rr = 0;
        for (int j = 0; j < XCDS; ++j) {
            int present = __hip_atomic_load(&regcnt[j], __ATOMIC_RELAXED,
                                            __HIP_MEMORY_SCOPE_AGENT) > 0;
            int owner = present ? j : list[rr++ % nz];
            owngrp[owner * 8 + owncnt[owner]] = j;
            owncnt[owner] += 1;
        }
    }
    grid.sync();

    int nblk = __hip_atomic_load(&regcnt[xcd], __ATOMIC_RELAXED, __HIP_MEMORY_SCOPE_AGENT);
    int nown = owncnt[xcd];

    int wave = tid >> 6;
    int lane = tid & 63;
    int rs   = lane >> 3;
    int u    = lane & 7;

    // half assignment (robust to nblk==1)
    int hfbeg, hfend, mywave, nwh;
    if (nblk >= 2) {
        int hf = slot & 1;
        hfbeg = hf; hfend = hf + 1;
        int nhb = (hf == 0) ? ((nblk + 1) >> 1) : (nblk >> 1);
        mywave = (slot >> 1) * (RNN_THREADS / 64) + wave;
        nwh = nhb * (RNN_THREADS / 64);
    } else {
        hfbeg = 0; hfend = 2;
        mywave = wave; nwh = RNN_THREADS / 64;
    }

    int* bc = &barcnt[xcd * 32];
    int* bgen = &bargen[xcd * 32];

    for (int t = 0; t < T_; ++t) {
        for (int oi = 0; oi < nown; ++oi) {
            int grp = owngrp[xcd * 8 + oi];
            for (int hf = hfbeg; hf < hfend; ++hf) {
                const unsigned short* src =
                    hg + (size_t)((grp * 2 + (t & 1)) * 2 + hf) * (H_ * 4);
                unsigned short* dst =
                    hg + (size_t)((grp * 2 + ((t + 1) & 1)) * 2 + hf) * (H_ * 4);

                // ---- fill sh with bf16 h_prev (sc0: bypass stale L1, hit L2) ----
                __syncthreads();   // prior readers of sh are done
                {
                    uint4 v0, v1;
                    const char* s = (const char*)src;
                    load2x16_sc0(s + (size_t)tid * 16,
                                 s + (size_t)(1024 + tid) * 16, v0, v1);
                    uint4* s4 = (uint4*)sh;
                    s4[tid]        = v0;
                    s4[1024 + tid] = v1;
                }
                __syncthreads();   // sh ready

                // ---- compute: hh SpMM rows + pre + tanh (guard-free padded CSR) ----
                for (int g = mywave; g < H_ / 8; g += nwh) {
                    int r  = g * 8 + rs;
                    int hb = hhp[r];
                    int len = hhp[r + 1] - hb;   // padded: uniform across group

                    // early pre load (u<8 index safe; consumed after reduce)
                    unsigned short pus =
                        pre[((size_t)(grp * 2 + hf) * T_ + t) * (H_ * 4) +
                            (size_t)r * 4 + u];

                    float a0 = 0.f, a1 = 0.f, a2 = 0.f, a3 = 0.f;
                    int kk = hb + u;
                    int2 pk = hhpack[kk];
                    for (int i = 0; i < len; i += 8) {
                        kk += 8;
                        int2 pkn = hhpack[kk];   // next-window prefetch (slack-padded)
                        uint2 hw = *(const uint2*)((const char*)sh + ((size_t)pk.x << 3));
                        float v = __int_as_float(pk.y);
                        a0 += v * __uint_as_float(hw.x << 16);
                        a1 += v * __uint_as_float(hw.x & 0xffff0000u);
                        a2 += v * __uint_as_float(hw.y << 16);
                        a3 += v * __uint_as_float(hw.y & 0xffff0000u);
                        pk = pkn;
                    }
                    #pragma unroll
                    for (int off = 1; off <= 4; off <<= 1) {
                        a0 += __shfl_xor(a0, off);
                        a1 += __shfl_xor(a1, off);
                        a2 += __shfl_xor(a2, off);
                        a3 += __shfl_xor(a3, off);
                    }
                    if (u < 4) {
                        float acc = (u == 0) ? a0 : (u == 1) ? a1 : (u == 2) ? a2 : a3;
                        float pv = __uint_as_float((unsigned int)pus << 16);
                        float h = tanhf(acc + pv);
                        dst[(size_t)r * 4 + u] = f2bf(h);
                        int b = grp * 8 + hf * 4 + u;
                        out[(size_t)b * T_ * H_ + (size_t)t * H_ + r] = h;
                    }
                }
            }
        }

        // ---- per-XCD barrier (no cache maintenance) ----
        __syncthreads();   // drains this block's h stores to L2 (vmcnt(0) before s_barrier)
        if (tid == 0) {
            asm volatile("s_waitcnt vmcnt(0)" ::: "memory");
            int target = t + 1;
            int old = __hip_atomic_fetch_add(bc, 1, __ATOMIC_RELAXED,
                                             __HIP_MEMORY_SCOPE_AGENT);
            if (old == nblk - 1) {
                __hip_atomic_store(bc, 0, __ATOMIC_RELAXED, __HIP_MEMORY_SCOPE_AGENT);
                __hip_atomic_store(bgen, target, __ATOMIC_RELAXED, __HIP_MEMORY_SCOPE_AGENT);
            } else {
                while (__hip_atomic_load(bgen, __ATOMIC_RELAXED,
                                         __HIP_MEMORY_SCOPE_AGENT) < target) {
                    __builtin_amdgcn_s_sleep(1);
                }
            }
        }
        __syncthreads();
    }
}

// ---------------- host launch ----------------
extern "C" void kernel_launch(void* const* d_in, const int* in_sizes, int n_in,
                              void* d_out, int out_size, void* d_ws, size_t ws_size,
                              hipStream_t stream) {
    const float* x       = (const float*)d_in[0];
    const float* ih_vals = (const float*)d_in[1];
    const float* hh_vals = (const float*)d_in[2];
    const float* hh_bias = (const float*)d_in[3];
    const int*   ih_rows = (const int*)d_in[4];
    const int*   ih_cols = (const int*)d_in[5];
    const int*   hh_rows = (const int*)d_in[6];
    const int*   hh_cols = (const int*)d_in[7];
    float* out = (float*)d_out;

    const int nnz_ih = in_sizes[1];
    const int nnz_hh = in_sizes[2];

    char* ws = (char*)d_ws;
    size_t off = 0;
    auto alloc = [&](size_t bytes) -> void* {
        off = (off + 255) & ~(size_t)255;
        void* p = ws + off;
        off += bytes;
        return p;
    };

    unsigned short* xT2 = (unsigned short*)alloc((size_t)T_ * 8 * I_ * 8 * sizeof(unsigned short));
    int*   ih_rp  = (int*)alloc((H_ + 1) * sizeof(int));
    int*   hh_rp  = (int*)alloc((H_ + 1) * sizeof(int));
    int*   hh_pcnt = (int*)alloc(H_ * sizeof(int));

    const int ZINTS = 4 * H_ + 64 + 8 * 32 + 8 * 32 + 8 + 64;
    int* zbase  = (int*)alloc((size_t)ZINTS * sizeof(int));
    int* ih_cnt = zbase;
    int* ih_cur = zbase + H_;
    int* hh_cnt = zbase + 2 * H_;
    int* hh_cur = zbase + 3 * H_;
    int* regcnt = zbase + 4 * H_;
    int* barcnt = regcnt + 64;
    int* bargen = barcnt + 8 * 32;
    int* owncnt = bargen + 8 * 32;
    int* owngrp = owncnt + 8;

    int2* ih_pack = (int2*)alloc((size_t)nnz_ih * sizeof(int2));
    size_t hh_pack_n = (size_t)2 * nnz_hh + 64;   // padded bound + prefetch slack
    int2* hh_pack = (int2*)alloc(hh_pack_n * sizeof(int2));
    unsigned short* hg = (unsigned short*)alloc((size_t)XCDS * 2 * 2 * H_ * 4 * sizeof(unsigned short)); // 1 MB
    unsigned short* pre = (unsigned short*)alloc((size_t)16 * T_ * H_ * 4 * sizeof(unsigned short)); // 67 MB

    hipMemsetAsync(zbase, 0, (size_t)ZINTS * sizeof(int), stream);
    hipMemsetAsync(hg, 0, (size_t)XCDS * 2 * 2 * H_ * 4 * sizeof(unsigned short), stream);
    hipMemsetAsync(hh_pack, 0, hh_pack_n * sizeof(int2), stream);

    transpose_x<<<dim3(I_ / 128, 8, T_), dim3(128, 8), 0, stream>>>(x, xT2);

    hist_rows<<<(nnz_ih + 255) / 256, 256, 0, stream>>>(ih_rows, nnz_ih, ih_cnt);
    scan_rows<<<1, 64, 0, stream>>>(ih_cnt, ih_rp, H_);
    scatter_pack<<<(nnz_ih + 255) / 256, 256, 0, stream>>>(ih_rows, ih_cols, ih_vals, nnz_ih,
                                                           ih_rp, ih_cur, ih_pack);
    hist_rows<<<(nnz_hh + 255) / 256, 256, 0, stream>>>(hh_rows, nnz_hh, hh_cnt);
    pad_counts<<<(H_ / 8 + 255) / 256, 256, 0, stream>>>(hh_cnt, hh_pcnt);
    scan_rows<<<1, 64, 0, stream>>>(hh_pcnt, hh_rp, H_);
    scatter_pack<<<(nnz_hh + 255) / 256, 256, 0, stream>>>(hh_rows, hh_cols, hh_vals, nnz_hh,
                                                           hh_rp, hh_cur, hh_pack);

    precompute_ih<<<dim3(H_ / 8 / 16, 8), dim3(1024), 0, stream>>>(xT2, ih_rp, ih_pack,
                                                                   hh_bias, pre);

    void* kargs[] = {
        (void*)&hh_rp, (void*)&hh_pack,
        (void*)&pre,
        (void*)&hg,
        (void*)&regcnt, (void*)&barcnt, (void*)&bargen,
        (void*)&owncnt, (void*)&owngrp,
        (void*)&out,
    };
    hipLaunchCooperativeKernel((const void*)rnn_steps, dim3(RNN_BLOCKS), dim3(RNN_THREADS),
                               kargs, 0, stream);
}